// Round 7
// baseline (756.412 us; speedup 1.0000x reference)
//
#include <hip/hip_runtime.h>
#include <math.h>

#define NBITS 7            // log2(nodes per bucket)
#define BNODES 128         // nodes per bucket
#define CHUNK 4096         // edges per partition block

// ---------------- GEMM: Y[n][o] = norm[n] * sum_f feat[n][f] * W[o][f] ----------------
__global__ __launch_bounds__(256) void gemm_kernel(
    const float* __restrict__ feat, const float* __restrict__ norm,
    const float* __restrict__ W, float* __restrict__ Y, int n_nodes) {
  __shared__ float sWt[64][132];   // [f][o] transposed
  __shared__ float sA[64][68];     // [node][f]
  const int t = threadIdx.x;
  const int node0 = blockIdx.x * 64;
  const int og = t & 31;
  const int ng = t >> 5;

  float acc[8][4];
#pragma unroll
  for (int j = 0; j < 8; ++j)
#pragma unroll
    for (int k = 0; k < 4; ++k) acc[j][k] = 0.f;

  for (int half = 0; half < 2; ++half) {
    __syncthreads();
#pragma unroll
    for (int k = 0; k < 8; ++k) {
      int e4 = k * 256 + t;
      int oo = e4 >> 4;
      int f4 = (e4 & 15) * 4;
      float4 w = *(const float4*)&W[oo * 128 + half * 64 + f4];
      sWt[f4 + 0][oo] = w.x; sWt[f4 + 1][oo] = w.y;
      sWt[f4 + 2][oo] = w.z; sWt[f4 + 3][oo] = w.w;
    }
#pragma unroll
    for (int k = 0; k < 4; ++k) {
      int e4 = k * 256 + t;
      int nn = e4 >> 4;
      int f4 = (e4 & 15) * 4;
      int node = node0 + nn;
      float4 a = (node < n_nodes)
                     ? *(const float4*)&feat[(size_t)node * 128 + half * 64 + f4]
                     : make_float4(0.f, 0.f, 0.f, 0.f);
      *(float4*)&sA[nn][f4] = a;
    }
    __syncthreads();
#pragma unroll 4
    for (int f = 0; f < 64; ++f) {
      float4 w = *(const float4*)&sWt[f][og * 4];
#pragma unroll
      for (int j = 0; j < 8; ++j) {
        float a = sA[ng * 8 + j][f];
        acc[j][0] += a * w.x; acc[j][1] += a * w.y;
        acc[j][2] += a * w.z; acc[j][3] += a * w.w;
      }
    }
  }
#pragma unroll
  for (int j = 0; j < 8; ++j) {
    int node = node0 + ng * 8 + j;
    if (node < n_nodes) {
      float nm = norm[node];
      float4 v = make_float4(acc[j][0] * nm, acc[j][1] * nm,
                             acc[j][2] * nm, acc[j][3] * nm);
      *(float4*)&Y[(size_t)node * 128 + og * 4] = v;
    }
  }
}

// ---------------- bucket histogram (LDS-staged) ----------------
__global__ __launch_bounds__(256) void hist_kernel(
    const int* __restrict__ dst, int* __restrict__ counts, int n_edges, int nb) {
  __shared__ int hc[512];
  int t = threadIdx.x;
  hc[t] = 0; hc[t + 256] = 0;
  __syncthreads();
  int n4 = n_edges >> 2;
  for (int i = blockIdx.x * blockDim.x + t; i < n4; i += gridDim.x * blockDim.x) {
    int4 d = ((const int4*)dst)[i];
    atomicAdd(&hc[d.x >> NBITS], 1);
    atomicAdd(&hc[d.y >> NBITS], 1);
    atomicAdd(&hc[d.z >> NBITS], 1);
    atomicAdd(&hc[d.w >> NBITS], 1);
  }
  int tail0 = n4 << 2;
  int idx = blockIdx.x * blockDim.x + t;
  if (idx < n_edges - tail0) atomicAdd(&hc[dst[tail0 + idx] >> NBITS], 1);
  __syncthreads();
  if (t < nb && hc[t]) atomicAdd(&counts[t], hc[t]);
  int t2 = t + 256;
  if (t2 < nb && hc[t2]) atomicAdd(&counts[t2], hc[t2]);
}

// ---------------- exclusive scan over nb (<=512) buckets ----------------
__global__ __launch_bounds__(512) void scan_kernel(
    const int* __restrict__ counts, int* __restrict__ bstart,
    int* __restrict__ cursor, int nb) {
  __shared__ int s[512];
  int t = threadIdx.x;
  int v = (t < nb) ? counts[t] : 0;
  s[t] = v;
  __syncthreads();
  for (int off = 1; off < 512; off <<= 1) {
    int u = (t >= off) ? s[t - off] : 0;
    __syncthreads();
    s[t] += u;
    __syncthreads();
  }
  if (t < nb) {
    int e = s[t] - v;
    bstart[t] = e;
    cursor[t] = e;
  }
}

// ---------------- partition: LDS counting-sort per chunk, dense flush ----------------
// record = src | (dst << 16)   (requires n_nodes <= 65536)
__global__ __launch_bounds__(256) void partition_kernel(
    const int* __restrict__ src, const int* __restrict__ dst,
    int* __restrict__ cursor, unsigned* __restrict__ recs, int n_edges, int nb) {
  __shared__ int lcount[512];
  __shared__ int lbase[512];
  __shared__ int gbase[512];
  __shared__ int aux[256];
  __shared__ unsigned stage[CHUNK];
  __shared__ int s_total;
  const int t = threadIdx.x;
  const int cbase = blockIdx.x * CHUNK;

  lcount[t] = 0; lcount[t + 256] = 0;
  __syncthreads();

  int es[16], ed[16], rk[16];
#pragma unroll
  for (int q = 0; q < 4; ++q) {
    int i4 = (cbase >> 2) + q * 256 + t;
    int e0 = i4 << 2;
    int4 sv, dv;
    if (e0 + 3 < n_edges) {
      sv = ((const int4*)src)[i4];
      dv = ((const int4*)dst)[i4];
    } else {
      sv.x = (e0 + 0 < n_edges) ? src[e0 + 0] : 0;
      sv.y = (e0 + 1 < n_edges) ? src[e0 + 1] : 0;
      sv.z = (e0 + 2 < n_edges) ? src[e0 + 2] : 0;
      sv.w = 0;
      dv.x = (e0 + 0 < n_edges) ? dst[e0 + 0] : -1;
      dv.y = (e0 + 1 < n_edges) ? dst[e0 + 1] : -1;
      dv.z = (e0 + 2 < n_edges) ? dst[e0 + 2] : -1;
      dv.w = -1;
    }
    es[q * 4 + 0] = sv.x; ed[q * 4 + 0] = dv.x;
    es[q * 4 + 1] = sv.y; ed[q * 4 + 1] = dv.y;
    es[q * 4 + 2] = sv.z; ed[q * 4 + 2] = dv.z;
    es[q * 4 + 3] = sv.w; ed[q * 4 + 3] = dv.w;
  }
#pragma unroll
  for (int k = 0; k < 16; ++k)
    rk[k] = (ed[k] >= 0) ? atomicAdd(&lcount[ed[k] >> NBITS], 1) : 0;
  __syncthreads();

  // block scan of lcount[512] -> lbase (exclusive)
  int a = lcount[2 * t] + lcount[2 * t + 1];
  aux[t] = a;
  __syncthreads();
  for (int off = 1; off < 256; off <<= 1) {
    int u = (t >= off) ? aux[t - off] : 0;
    __syncthreads();
    aux[t] += u;
    __syncthreads();
  }
  int ex = aux[t] - a;
  lbase[2 * t] = ex;
  lbase[2 * t + 1] = ex + lcount[2 * t];
  if (t == 255) s_total = aux[255];
  __syncthreads();

  // reserve global ranges
  for (int b = t; b < nb; b += 256)
    gbase[b] = (lcount[b] > 0) ? atomicAdd(&cursor[b], lcount[b]) : 0;
  __syncthreads();

  // scatter into LDS stage (bucket-sorted within chunk)
#pragma unroll
  for (int k = 0; k < 16; ++k) {
    if (ed[k] >= 0) {
      int b = ed[k] >> NBITS;
      stage[lbase[b] + rk[k]] = (unsigned)es[k] | ((unsigned)ed[k] << 16);
    }
  }
  __syncthreads();

  // dense copy out: consecutive r -> consecutive global positions per bucket
  int total = s_total;
  for (int r = t; r < total; r += 256) {
    unsigned rec = stage[r];
    int b = (int)(rec >> (16 + NBITS));
    recs[gbase[b] + (r - lbase[b])] = rec;
  }
}

// ---------------- gather: LDS 128x128 f32 tile per bucket + fused tanh ----------------
__global__ __launch_bounds__(256) void gather_kernel(
    const float* __restrict__ Y, const unsigned* __restrict__ recs,
    const int* __restrict__ bstart, const int* __restrict__ counts,
    const float* __restrict__ norm, const float* __restrict__ bias,
    float* __restrict__ out, int n_nodes) {
  __shared__ float tile[BNODES * 128];
  const int t = threadIdx.x;
  const int b = blockIdx.x;
  const int node0 = b << NBITS;

#pragma unroll
  for (int k = 0; k < 16; ++k)
    *(float4*)&tile[(k * 256 + t) * 4] = make_float4(0.f, 0.f, 0.f, 0.f);
  __syncthreads();

  const int lane = t & 63;
  const int w = t >> 6;
  const float2* __restrict__ Y2 = (const float2*)Y;
  int cbeg = bstart[b];
  int cnt = counts[b];
  int wbeg = cbeg + (cnt * w) / 4;
  int wend = cbeg + (cnt * (w + 1)) / 4;

  for (int base = wbeg; base < wend; base += 64) {
    int m = wend - base;
    if (m > 64) m = 64;
    unsigned rp = 0;
    if (lane < m) rp = recs[base + lane];
    int g = 0;
    for (; g + 4 <= m; g += 4) {
      unsigned p0 = (unsigned)__builtin_amdgcn_readlane((int)rp, g + 0);
      unsigned p1 = (unsigned)__builtin_amdgcn_readlane((int)rp, g + 1);
      unsigned p2 = (unsigned)__builtin_amdgcn_readlane((int)rp, g + 2);
      unsigned p3 = (unsigned)__builtin_amdgcn_readlane((int)rp, g + 3);
      float2 v0 = Y2[(size_t)(p0 & 0xffffu) * 64 + lane];
      float2 v1 = Y2[(size_t)(p1 & 0xffffu) * 64 + lane];
      float2 v2 = Y2[(size_t)(p2 & 0xffffu) * 64 + lane];
      float2 v3 = Y2[(size_t)(p3 & 0xffffu) * 64 + lane];
      int r0 = ((p0 >> 16) & (BNODES - 1)) << 7;
      int r1 = ((p1 >> 16) & (BNODES - 1)) << 7;
      int r2 = ((p2 >> 16) & (BNODES - 1)) << 7;
      int r3 = ((p3 >> 16) & (BNODES - 1)) << 7;
      atomicAdd(&tile[r0 + 2 * lane],     v0.x);
      atomicAdd(&tile[r0 + 2 * lane + 1], v0.y);
      atomicAdd(&tile[r1 + 2 * lane],     v1.x);
      atomicAdd(&tile[r1 + 2 * lane + 1], v1.y);
      atomicAdd(&tile[r2 + 2 * lane],     v2.x);
      atomicAdd(&tile[r2 + 2 * lane + 1], v2.y);
      atomicAdd(&tile[r3 + 2 * lane],     v3.x);
      atomicAdd(&tile[r3 + 2 * lane + 1], v3.y);
    }
    for (; g < m; ++g) {
      unsigned p = (unsigned)__builtin_amdgcn_readlane((int)rp, g);
      float2 v = Y2[(size_t)(p & 0xffffu) * 64 + lane];
      int r = ((p >> 16) & (BNODES - 1)) << 7;
      atomicAdd(&tile[r + 2 * lane],     v.x);
      atomicAdd(&tile[r + 2 * lane + 1], v.y);
    }
  }
  __syncthreads();

  // epilogue: out = tanh(tile * norm + b), coalesced float4
#pragma unroll
  for (int k = 0; k < 16; ++k) {
    int idx = k * 256 + t;       // float4 index within tile
    int row = idx >> 5;
    int c4 = idx & 31;
    int node = node0 + row;
    if (node < n_nodes) {
      float4 v = *(float4*)&tile[(row << 7) + c4 * 4];
      float nm = norm[node];
      float4 bb = ((const float4*)bias)[c4];
      float4 h;
      h.x = tanhf(fmaf(v.x, nm, bb.x));
      h.y = tanhf(fmaf(v.y, nm, bb.y));
      h.z = tanhf(fmaf(v.z, nm, bb.z));
      h.w = tanhf(fmaf(v.w, nm, bb.w));
      *(float4*)&out[((size_t)node << 7) + c4 * 4] = h;
    }
  }
}

extern "C" void kernel_launch(void* const* d_in, const int* in_sizes, int n_in,
                              void* d_out, int out_size, void* d_ws, size_t ws_size,
                              hipStream_t stream) {
  const float* feat = (const float*)d_in[0];   // [N,128]
  const float* norm = (const float*)d_in[1];   // [N,1]
  const float* W    = (const float*)d_in[2];   // [128,128]
  const float* b    = (const float*)d_in[3];   // [128]
  const int* src    = (const int*)d_in[4];     // [E]
  const int* dst    = (const int*)d_in[5];     // [E]
  float* out        = (float*)d_out;           // [N,128]

  const int n_nodes = in_sizes[1];
  const int n_edges = in_sizes[4];
  const int nb = (n_nodes + BNODES - 1) / BNODES;   // 391

  // workspace layout
  char* base = (char*)d_ws;
  float* Y = (float*)base;                          // N*128 f32
  size_t off = (size_t)n_nodes * 128 * sizeof(float);
  off = (off + 255) & ~(size_t)255;
  int* counts = (int*)(base + off); off += (size_t)nb * 4;
  off = (off + 255) & ~(size_t)255;
  int* bstart = (int*)(base + off); off += (size_t)nb * 4;
  off = (off + 255) & ~(size_t)255;
  int* cursor = (int*)(base + off); off += (size_t)nb * 4;
  off = (off + 255) & ~(size_t)255;
  unsigned* recs = (unsigned*)(base + off); off += (size_t)n_edges * 4;

  // 1) Y = norm * (feat @ W^T)
  int gblocks = (n_nodes + 63) / 64;
  gemm_kernel<<<gblocks, 256, 0, stream>>>(feat, norm, W, Y, n_nodes);

  // 2) bucket histogram
  hipMemsetAsync(counts, 0, (size_t)nb * sizeof(int), stream);
  hist_kernel<<<256, 256, 0, stream>>>(dst, counts, n_edges, nb);

  // 3) scan -> bucket starts + cursors
  scan_kernel<<<1, 512, 0, stream>>>(counts, bstart, cursor, nb);

  // 4) partition edges into dst-buckets (dense writes)
  int chunks = (n_edges + CHUNK - 1) / CHUNK;
  partition_kernel<<<chunks, 256, 0, stream>>>(src, dst, cursor, recs, n_edges, nb);

  // 5) per-bucket LDS-tile aggregation + fused tanh
  gather_kernel<<<nb, 256, 0, stream>>>(Y, recs, bstart, counts, norm, b, out, n_nodes);
}

// Round 8
// 130.687 us; speedup vs baseline: 5.7880x; 5.7880x over previous
//
#include <hip/hip_runtime.h>
#include <math.h>

#define NBITS 7            // log2(nodes per bucket)
#define BNODES 128         // nodes per bucket
#define CHUNK 2048         // edges per partition block

// ---------------- GEMM: Y[n][o] = norm[n] * sum_f feat[n][f] * W[o][f] ----------------
__global__ __launch_bounds__(256) void gemm_kernel(
    const float* __restrict__ feat, const float* __restrict__ norm,
    const float* __restrict__ W, float* __restrict__ Y, int n_nodes) {
  __shared__ float sWt[64][132];   // [f][o] transposed
  __shared__ float sA[64][68];     // [node][f]
  const int t = threadIdx.x;
  const int node0 = blockIdx.x * 64;
  const int og = t & 31;
  const int ng = t >> 5;

  float acc[8][4];
#pragma unroll
  for (int j = 0; j < 8; ++j)
#pragma unroll
    for (int k = 0; k < 4; ++k) acc[j][k] = 0.f;

  for (int half = 0; half < 2; ++half) {
    __syncthreads();
#pragma unroll
    for (int k = 0; k < 8; ++k) {
      int e4 = k * 256 + t;
      int oo = e4 >> 4;
      int f4 = (e4 & 15) * 4;
      float4 w = *(const float4*)&W[oo * 128 + half * 64 + f4];
      sWt[f4 + 0][oo] = w.x; sWt[f4 + 1][oo] = w.y;
      sWt[f4 + 2][oo] = w.z; sWt[f4 + 3][oo] = w.w;
    }
#pragma unroll
    for (int k = 0; k < 4; ++k) {
      int e4 = k * 256 + t;
      int nn = e4 >> 4;
      int f4 = (e4 & 15) * 4;
      int node = node0 + nn;
      float4 a = (node < n_nodes)
                     ? *(const float4*)&feat[(size_t)node * 128 + half * 64 + f4]
                     : make_float4(0.f, 0.f, 0.f, 0.f);
      *(float4*)&sA[nn][f4] = a;
    }
    __syncthreads();
#pragma unroll 4
    for (int f = 0; f < 64; ++f) {
      float4 w = *(const float4*)&sWt[f][og * 4];
#pragma unroll
      for (int j = 0; j < 8; ++j) {
        float a = sA[ng * 8 + j][f];
        acc[j][0] += a * w.x; acc[j][1] += a * w.y;
        acc[j][2] += a * w.z; acc[j][3] += a * w.w;
      }
    }
  }
#pragma unroll
  for (int j = 0; j < 8; ++j) {
    int node = node0 + ng * 8 + j;
    if (node < n_nodes) {
      float nm = norm[node];
      float4 v = make_float4(acc[j][0] * nm, acc[j][1] * nm,
                             acc[j][2] * nm, acc[j][3] * nm);
      *(float4*)&Y[(size_t)node * 128 + og * 4] = v;
    }
  }
}

// ---------------- coarse bucket histogram (LDS-staged) ----------------
__global__ __launch_bounds__(256) void hist_kernel(
    const int* __restrict__ dst, int* __restrict__ counts, int n_edges, int nb) {
  __shared__ int hc[512];
  int t = threadIdx.x;
  hc[t] = 0; hc[t + 256] = 0;
  __syncthreads();
  int n4 = n_edges >> 2;
  for (int i = blockIdx.x * blockDim.x + t; i < n4; i += gridDim.x * blockDim.x) {
    int4 d = ((const int4*)dst)[i];
    atomicAdd(&hc[d.x >> NBITS], 1);
    atomicAdd(&hc[d.y >> NBITS], 1);
    atomicAdd(&hc[d.z >> NBITS], 1);
    atomicAdd(&hc[d.w >> NBITS], 1);
  }
  int tail0 = n4 << 2;
  int idx = blockIdx.x * blockDim.x + t;
  if (idx < n_edges - tail0) atomicAdd(&hc[dst[tail0 + idx] >> NBITS], 1);
  __syncthreads();
  if (t < nb && hc[t]) atomicAdd(&counts[t], hc[t]);
  int t2 = t + 256;
  if (t2 < nb && hc[t2]) atomicAdd(&counts[t2], hc[t2]);
}

// ---------------- exclusive scan over nb (<=512) buckets ----------------
__global__ __launch_bounds__(512) void scan_kernel(
    const int* __restrict__ counts, int* __restrict__ bstart,
    int* __restrict__ cursor, int nb) {
  __shared__ int s[512];
  int t = threadIdx.x;
  int v = (t < nb) ? counts[t] : 0;
  s[t] = v;
  __syncthreads();
  for (int off = 1; off < 512; off <<= 1) {
    int u = (t >= off) ? s[t - off] : 0;
    __syncthreads();
    s[t] += u;
    __syncthreads();
  }
  if (t < nb) {
    int e = s[t] - v;
    bstart[t] = e;
    cursor[t] = e;
  }
}

// ---------------- partition: LDS counting-sort per chunk, dense flush ----------------
// record = src | (dst << 16)   (requires n_nodes <= 65536)
__global__ __launch_bounds__(256) void partition_kernel(
    const int* __restrict__ src, const int* __restrict__ dst,
    int* __restrict__ cursor, unsigned* __restrict__ recs, int n_edges, int nb) {
  __shared__ int lcount[512];
  __shared__ int lbase[512];
  __shared__ int gbase[512];
  __shared__ int aux[256];
  __shared__ unsigned stage[CHUNK];
  __shared__ int s_total;
  const int t = threadIdx.x;
  const int cbase = blockIdx.x * CHUNK;

  lcount[t] = 0; lcount[t + 256] = 0;
  __syncthreads();

  int es[8], ed[8], rk[8];
#pragma unroll
  for (int q = 0; q < 2; ++q) {
    int i4 = (cbase >> 2) + q * 256 + t;
    int e0 = i4 << 2;
    int4 sv, dv;
    if (e0 + 3 < n_edges) {
      sv = ((const int4*)src)[i4];
      dv = ((const int4*)dst)[i4];
    } else {
      sv.x = (e0 + 0 < n_edges) ? src[e0 + 0] : 0;
      sv.y = (e0 + 1 < n_edges) ? src[e0 + 1] : 0;
      sv.z = (e0 + 2 < n_edges) ? src[e0 + 2] : 0;
      sv.w = 0;
      dv.x = (e0 + 0 < n_edges) ? dst[e0 + 0] : -1;
      dv.y = (e0 + 1 < n_edges) ? dst[e0 + 1] : -1;
      dv.z = (e0 + 2 < n_edges) ? dst[e0 + 2] : -1;
      dv.w = -1;
    }
    es[q * 4 + 0] = sv.x; ed[q * 4 + 0] = dv.x;
    es[q * 4 + 1] = sv.y; ed[q * 4 + 1] = dv.y;
    es[q * 4 + 2] = sv.z; ed[q * 4 + 2] = dv.z;
    es[q * 4 + 3] = sv.w; ed[q * 4 + 3] = dv.w;
  }
#pragma unroll
  for (int k = 0; k < 8; ++k)
    rk[k] = (ed[k] >= 0) ? atomicAdd(&lcount[ed[k] >> NBITS], 1) : 0;
  __syncthreads();

  // block scan of lcount[512] -> lbase (exclusive)
  int a = lcount[2 * t] + lcount[2 * t + 1];
  aux[t] = a;
  __syncthreads();
  for (int off = 1; off < 256; off <<= 1) {
    int u = (t >= off) ? aux[t - off] : 0;
    __syncthreads();
    aux[t] += u;
    __syncthreads();
  }
  int ex = aux[t] - a;
  lbase[2 * t] = ex;
  lbase[2 * t + 1] = ex + lcount[2 * t];
  if (t == 255) s_total = aux[255];
  __syncthreads();

  // reserve global ranges
  for (int b = t; b < nb; b += 256)
    gbase[b] = (lcount[b] > 0) ? atomicAdd(&cursor[b], lcount[b]) : 0;
  __syncthreads();

  // scatter into LDS stage (bucket-sorted within chunk)
#pragma unroll
  for (int k = 0; k < 8; ++k) {
    if (ed[k] >= 0) {
      int b = ed[k] >> NBITS;
      stage[lbase[b] + rk[k]] = (unsigned)es[k] | ((unsigned)ed[k] << 16);
    }
  }
  __syncthreads();

  // dense copy out: consecutive r -> consecutive global positions per bucket
  int total = s_total;
  for (int r = t; r < total; r += 256) {
    unsigned rec = stage[r];
    int b = (int)(rec >> (16 + NBITS));
    recs[gbase[b] + (r - lbase[b])] = rec;
  }
}

// ---------------- localize: per-bucket counting sort by node -> per-node CSR ----------------
__global__ __launch_bounds__(256) void localize_kernel(
    const unsigned* __restrict__ recs, const int* __restrict__ bstart,
    const int* __restrict__ bcounts, int* __restrict__ sorted_src,
    int* __restrict__ row_start, int* __restrict__ counts_d, int n_nodes) {
  __shared__ int lc[BNODES];
  __shared__ int ls[BNODES];
  __shared__ int cur[BNODES];
  const int t = threadIdx.x;
  const int b = blockIdx.x;
  const int cbeg = bstart[b];
  const int cnt = bcounts[b];

  if (t < BNODES) lc[t] = 0;
  __syncthreads();
  for (int i = t; i < cnt; i += 256) {
    unsigned rec = recs[cbeg + i];
    atomicAdd(&lc[(rec >> 16) & (BNODES - 1)], 1);
  }
  __syncthreads();
  if (t < BNODES) ls[t] = lc[t];
  __syncthreads();
  for (int off = 1; off < BNODES; off <<= 1) {
    int u = (t < BNODES && t >= off) ? ls[t - off] : 0;
    __syncthreads();
    if (t < BNODES) ls[t] += u;
    __syncthreads();
  }
  if (t < BNODES) {
    int ex = ls[t] - lc[t];       // exclusive prefix within bucket
    cur[t] = ex;
    int node = (b << NBITS) + t;
    if (node < n_nodes) {
      counts_d[node] = lc[t];
      row_start[node] = cbeg + ex;
    }
  }
  __syncthreads();
  for (int i = t; i < cnt; i += 256) {
    unsigned rec = recs[cbeg + i];
    int nl = (rec >> 16) & (BNODES - 1);
    int p = atomicAdd(&cur[nl], 1);
    sorted_src[cbeg + p] = (int)(rec & 0xffffu);
  }
}

// ---------------- gather-reduce + fused tanh ----------------
// one 64-lane wave per node; float2 per lane covers the full 512B row; unroll 8
__global__ __launch_bounds__(256) void gather_kernel(
    const float* __restrict__ Y, const int* __restrict__ sorted_src,
    const int* __restrict__ row_start, const int* __restrict__ counts_d,
    const float* __restrict__ norm, const float* __restrict__ b,
    float* __restrict__ out, int n_nodes) {
  int node = blockIdx.x * 4 + (threadIdx.x >> 6);
  if (node >= n_nodes) return;
  int lane = threadIdx.x & 63;
  int beg = row_start[node];
  int cnt = counts_d[node];
  const float2* Y2 = (const float2*)Y;
  float accx = 0.f, accy = 0.f;
  int i = beg, end = beg + cnt;
  for (; i + 8 <= end; i += 8) {
    int s0 = sorted_src[i + 0];
    int s1 = sorted_src[i + 1];
    int s2 = sorted_src[i + 2];
    int s3 = sorted_src[i + 3];
    int s4 = sorted_src[i + 4];
    int s5 = sorted_src[i + 5];
    int s6 = sorted_src[i + 6];
    int s7 = sorted_src[i + 7];
    float2 v0 = Y2[(size_t)s0 * 64 + lane];
    float2 v1 = Y2[(size_t)s1 * 64 + lane];
    float2 v2 = Y2[(size_t)s2 * 64 + lane];
    float2 v3 = Y2[(size_t)s3 * 64 + lane];
    float2 v4 = Y2[(size_t)s4 * 64 + lane];
    float2 v5 = Y2[(size_t)s5 * 64 + lane];
    float2 v6 = Y2[(size_t)s6 * 64 + lane];
    float2 v7 = Y2[(size_t)s7 * 64 + lane];
    accx += (v0.x + v1.x) + (v2.x + v3.x) + ((v4.x + v5.x) + (v6.x + v7.x));
    accy += (v0.y + v1.y) + (v2.y + v3.y) + ((v4.y + v5.y) + (v6.y + v7.y));
  }
  for (; i + 4 <= end; i += 4) {
    int s0 = sorted_src[i + 0];
    int s1 = sorted_src[i + 1];
    int s2 = sorted_src[i + 2];
    int s3 = sorted_src[i + 3];
    float2 v0 = Y2[(size_t)s0 * 64 + lane];
    float2 v1 = Y2[(size_t)s1 * 64 + lane];
    float2 v2 = Y2[(size_t)s2 * 64 + lane];
    float2 v3 = Y2[(size_t)s3 * 64 + lane];
    accx += (v0.x + v1.x) + (v2.x + v3.x);
    accy += (v0.y + v1.y) + (v2.y + v3.y);
  }
  for (; i < end; ++i) {
    int s = sorted_src[i];
    float2 v = Y2[(size_t)s * 64 + lane];
    accx += v.x;
    accy += v.y;
  }
  float nm = norm[node];
  float2 bb = ((const float2*)b)[lane];
  float2 h;
  h.x = tanhf(accx * nm + bb.x);
  h.y = tanhf(accy * nm + bb.y);
  ((float2*)out)[(size_t)node * 64 + lane] = h;
}

extern "C" void kernel_launch(void* const* d_in, const int* in_sizes, int n_in,
                              void* d_out, int out_size, void* d_ws, size_t ws_size,
                              hipStream_t stream) {
  const float* feat = (const float*)d_in[0];   // [N,128]
  const float* norm = (const float*)d_in[1];   // [N,1]
  const float* W    = (const float*)d_in[2];   // [128,128]
  const float* b    = (const float*)d_in[3];   // [128]
  const int* src    = (const int*)d_in[4];     // [E]
  const int* dst    = (const int*)d_in[5];     // [E]
  float* out        = (float*)d_out;           // [N,128]

  const int n_nodes = in_sizes[1];
  const int n_edges = in_sizes[4];
  const int nb = (n_nodes + BNODES - 1) / BNODES;   // 391

  // workspace layout
  char* base = (char*)d_ws;
  float* Y = (float*)base;                          // N*128 f32
  size_t off = (size_t)n_nodes * 128 * sizeof(float);
  off = (off + 255) & ~(size_t)255;
  int* counts = (int*)(base + off); off += (size_t)nb * 4;     // coarse bucket counts
  off = (off + 255) & ~(size_t)255;
  int* bstart = (int*)(base + off); off += (size_t)nb * 4;
  off = (off + 255) & ~(size_t)255;
  int* cursor = (int*)(base + off); off += (size_t)nb * 4;
  off = (off + 255) & ~(size_t)255;
  unsigned* recs = (unsigned*)(base + off); off += (size_t)n_edges * 4;
  off = (off + 255) & ~(size_t)255;
  int* sorted_src = (int*)(base + off); off += (size_t)n_edges * 4;
  off = (off + 255) & ~(size_t)255;
  int* row_start = (int*)(base + off); off += (size_t)n_nodes * 4;
  off = (off + 255) & ~(size_t)255;
  int* counts_d = (int*)(base + off); off += (size_t)n_nodes * 4;

  // 1) Y = norm * (feat @ W^T)
  int gblocks = (n_nodes + 63) / 64;
  gemm_kernel<<<gblocks, 256, 0, stream>>>(feat, norm, W, Y, n_nodes);

  // 2) coarse bucket histogram
  hipMemsetAsync(counts, 0, (size_t)nb * sizeof(int), stream);
  hist_kernel<<<256, 256, 0, stream>>>(dst, counts, n_edges, nb);

  // 3) scan -> bucket starts + cursors
  scan_kernel<<<1, 512, 0, stream>>>(counts, bstart, cursor, nb);

  // 4) partition edges into dst-buckets (dense writes)
  int chunks = (n_edges + CHUNK - 1) / CHUNK;
  partition_kernel<<<chunks, 256, 0, stream>>>(src, dst, cursor, recs, n_edges, nb);

  // 5) per-bucket counting sort -> per-node CSR (bucket-local traffic only)
  localize_kernel<<<nb, 256, 0, stream>>>(recs, bstart, counts, sorted_src,
                                          row_start, counts_d, n_nodes);

  // 6) wave-per-node gather-reduce + fused tanh(norm*agg + b)
  int nblocks = (n_nodes + 3) / 4;
  gather_kernel<<<nblocks, 256, 0, stream>>>(Y, sorted_src, row_start, counts_d,
                                             norm, b, out, n_nodes);
}

// Round 9
// 113.885 us; speedup vs baseline: 6.6419x; 1.1475x over previous
//
#include <hip/hip_runtime.h>
#include <hip/hip_fp16.h>
#include <math.h>

#define NBITS 7            // log2(nodes per bucket)
#define BNODES 128         // nodes per bucket
#define CHUNK 2048         // edges per partition block

__device__ __forceinline__ unsigned hpack(float a, float b) {
  __half2 h = __floats2half2_rn(a, b);
  return *reinterpret_cast<unsigned*>(&h);
}

// ---------------- GEMM: Yh[n] = fp16( norm[n] * (feat[n] @ W^T) ) ----------------
// Yh row = 64 uints; uint j holds features (2j, 2j+1) as half2.
__global__ __launch_bounds__(256) void gemm_kernel(
    const float* __restrict__ feat, const float* __restrict__ norm,
    const float* __restrict__ W, unsigned* __restrict__ Yh, int n_nodes) {
  __shared__ float sWt[64][132];   // [f][o] transposed
  __shared__ float sA[64][68];     // [node][f]
  const int t = threadIdx.x;
  const int node0 = blockIdx.x * 64;
  const int og = t & 31;           // outputs og*4 .. og*4+3
  const int ng = t >> 5;

  float acc[8][4];
#pragma unroll
  for (int j = 0; j < 8; ++j)
#pragma unroll
    for (int k = 0; k < 4; ++k) acc[j][k] = 0.f;

  for (int half = 0; half < 2; ++half) {
    __syncthreads();
#pragma unroll
    for (int k = 0; k < 8; ++k) {
      int e4 = k * 256 + t;
      int oo = e4 >> 4;
      int f4 = (e4 & 15) * 4;
      float4 w = *(const float4*)&W[oo * 128 + half * 64 + f4];
      sWt[f4 + 0][oo] = w.x; sWt[f4 + 1][oo] = w.y;
      sWt[f4 + 2][oo] = w.z; sWt[f4 + 3][oo] = w.w;
    }
#pragma unroll
    for (int k = 0; k < 4; ++k) {
      int e4 = k * 256 + t;
      int nn = e4 >> 4;
      int f4 = (e4 & 15) * 4;
      int node = node0 + nn;
      float4 a = (node < n_nodes)
                     ? *(const float4*)&feat[(size_t)node * 128 + half * 64 + f4]
                     : make_float4(0.f, 0.f, 0.f, 0.f);
      *(float4*)&sA[nn][f4] = a;
    }
    __syncthreads();
#pragma unroll 4
    for (int f = 0; f < 64; ++f) {
      float4 w = *(const float4*)&sWt[f][og * 4];
#pragma unroll
      for (int j = 0; j < 8; ++j) {
        float a = sA[ng * 8 + j][f];
        acc[j][0] += a * w.x; acc[j][1] += a * w.y;
        acc[j][2] += a * w.z; acc[j][3] += a * w.w;
      }
    }
  }
#pragma unroll
  for (int j = 0; j < 8; ++j) {
    int node = node0 + ng * 8 + j;
    if (node < n_nodes) {
      float nm = norm[node];
      uint2 u;
      u.x = hpack(acc[j][0] * nm, acc[j][1] * nm);   // features og*4, og*4+1
      u.y = hpack(acc[j][2] * nm, acc[j][3] * nm);   // features og*4+2, og*4+3
      ((uint2*)Yh)[(size_t)node * 32 + og] = u;
    }
  }
}

// ---------------- coarse bucket histogram (LDS-staged) ----------------
__global__ __launch_bounds__(256) void hist_kernel(
    const int* __restrict__ dst, int* __restrict__ counts, int n_edges, int nb) {
  __shared__ int hc[512];
  int t = threadIdx.x;
  hc[t] = 0; hc[t + 256] = 0;
  __syncthreads();
  int n4 = n_edges >> 2;
  for (int i = blockIdx.x * blockDim.x + t; i < n4; i += gridDim.x * blockDim.x) {
    int4 d = ((const int4*)dst)[i];
    atomicAdd(&hc[d.x >> NBITS], 1);
    atomicAdd(&hc[d.y >> NBITS], 1);
    atomicAdd(&hc[d.z >> NBITS], 1);
    atomicAdd(&hc[d.w >> NBITS], 1);
  }
  int tail0 = n4 << 2;
  int idx = blockIdx.x * blockDim.x + t;
  if (idx < n_edges - tail0) atomicAdd(&hc[dst[tail0 + idx] >> NBITS], 1);
  __syncthreads();
  if (t < nb && hc[t]) atomicAdd(&counts[t], hc[t]);
  int t2 = t + 256;
  if (t2 < nb && hc[t2]) atomicAdd(&counts[t2], hc[t2]);
}

// ---------------- exclusive scan over nb (<=512) buckets ----------------
__global__ __launch_bounds__(512) void scan_kernel(
    const int* __restrict__ counts, int* __restrict__ bstart,
    int* __restrict__ cursor, int nb) {
  __shared__ int s[512];
  int t = threadIdx.x;
  int v = (t < nb) ? counts[t] : 0;
  s[t] = v;
  __syncthreads();
  for (int off = 1; off < 512; off <<= 1) {
    int u = (t >= off) ? s[t - off] : 0;
    __syncthreads();
    s[t] += u;
    __syncthreads();
  }
  if (t < nb) {
    int e = s[t] - v;
    bstart[t] = e;
    cursor[t] = e;
  }
}

// ---------------- partition: LDS counting-sort per chunk, dense flush ----------------
// record = src | (dst << 16)   (requires n_nodes <= 65536)
__global__ __launch_bounds__(256) void partition_kernel(
    const int* __restrict__ src, const int* __restrict__ dst,
    int* __restrict__ cursor, unsigned* __restrict__ recs, int n_edges, int nb) {
  __shared__ int lcount[512];
  __shared__ int lbase[512];
  __shared__ int gbase[512];
  __shared__ int aux[256];
  __shared__ unsigned stage[CHUNK];
  __shared__ int s_total;
  const int t = threadIdx.x;
  const int cbase = blockIdx.x * CHUNK;

  lcount[t] = 0; lcount[t + 256] = 0;
  __syncthreads();

  int es[8], ed[8], rk[8];
#pragma unroll
  for (int q = 0; q < 2; ++q) {
    int i4 = (cbase >> 2) + q * 256 + t;
    int e0 = i4 << 2;
    int4 sv, dv;
    if (e0 + 3 < n_edges) {
      sv = ((const int4*)src)[i4];
      dv = ((const int4*)dst)[i4];
    } else {
      sv.x = (e0 + 0 < n_edges) ? src[e0 + 0] : 0;
      sv.y = (e0 + 1 < n_edges) ? src[e0 + 1] : 0;
      sv.z = (e0 + 2 < n_edges) ? src[e0 + 2] : 0;
      sv.w = 0;
      dv.x = (e0 + 0 < n_edges) ? dst[e0 + 0] : -1;
      dv.y = (e0 + 1 < n_edges) ? dst[e0 + 1] : -1;
      dv.z = (e0 + 2 < n_edges) ? dst[e0 + 2] : -1;
      dv.w = -1;
    }
    es[q * 4 + 0] = sv.x; ed[q * 4 + 0] = dv.x;
    es[q * 4 + 1] = sv.y; ed[q * 4 + 1] = dv.y;
    es[q * 4 + 2] = sv.z; ed[q * 4 + 2] = dv.z;
    es[q * 4 + 3] = sv.w; ed[q * 4 + 3] = dv.w;
  }
#pragma unroll
  for (int k = 0; k < 8; ++k)
    rk[k] = (ed[k] >= 0) ? atomicAdd(&lcount[ed[k] >> NBITS], 1) : 0;
  __syncthreads();

  // block scan of lcount[512] -> lbase (exclusive)
  int a = lcount[2 * t] + lcount[2 * t + 1];
  aux[t] = a;
  __syncthreads();
  for (int off = 1; off < 256; off <<= 1) {
    int u = (t >= off) ? aux[t - off] : 0;
    __syncthreads();
    aux[t] += u;
    __syncthreads();
  }
  int ex = aux[t] - a;
  lbase[2 * t] = ex;
  lbase[2 * t + 1] = ex + lcount[2 * t];
  if (t == 255) s_total = aux[255];
  __syncthreads();

  // reserve global ranges
  for (int b = t; b < nb; b += 256)
    gbase[b] = (lcount[b] > 0) ? atomicAdd(&cursor[b], lcount[b]) : 0;
  __syncthreads();

  // scatter into LDS stage (bucket-sorted within chunk)
#pragma unroll
  for (int k = 0; k < 8; ++k) {
    if (ed[k] >= 0) {
      int b = ed[k] >> NBITS;
      stage[lbase[b] + rk[k]] = (unsigned)es[k] | ((unsigned)ed[k] << 16);
    }
  }
  __syncthreads();

  // dense copy out: consecutive r -> consecutive global positions per bucket
  int total = s_total;
  for (int r = t; r < total; r += 256) {
    unsigned rec = stage[r];
    int b = (int)(rec >> (16 + NBITS));
    recs[gbase[b] + (r - lbase[b])] = rec;
  }
}

// ---------------- localize: per-bucket counting sort by node -> per-node CSR ----------------
__global__ __launch_bounds__(256) void localize_kernel(
    const unsigned* __restrict__ recs, const int* __restrict__ bstart,
    const int* __restrict__ bcounts, int* __restrict__ sorted_src,
    int* __restrict__ row_start, int* __restrict__ counts_d, int n_nodes) {
  __shared__ int lc[BNODES];
  __shared__ int ls[BNODES];
  __shared__ int cur[BNODES];
  const int t = threadIdx.x;
  const int b = blockIdx.x;
  const int cbeg = bstart[b];
  const int cnt = bcounts[b];

  if (t < BNODES) lc[t] = 0;
  __syncthreads();
  for (int i = t; i < cnt; i += 256) {
    unsigned rec = recs[cbeg + i];
    atomicAdd(&lc[(rec >> 16) & (BNODES - 1)], 1);
  }
  __syncthreads();
  if (t < BNODES) ls[t] = lc[t];
  __syncthreads();
  for (int off = 1; off < BNODES; off <<= 1) {
    int u = (t < BNODES && t >= off) ? ls[t - off] : 0;
    __syncthreads();
    if (t < BNODES) ls[t] += u;
    __syncthreads();
  }
  if (t < BNODES) {
    int ex = ls[t] - lc[t];       // exclusive prefix within bucket
    cur[t] = ex;
    int node = (b << NBITS) + t;
    if (node < n_nodes) {
      counts_d[node] = lc[t];
      row_start[node] = cbeg + ex;
    }
  }
  __syncthreads();
  for (int i = t; i < cnt; i += 256) {
    unsigned rec = recs[cbeg + i];
    int nl = (rec >> 16) & (BNODES - 1);
    int p = atomicAdd(&cur[nl], 1);
    sorted_src[cbeg + p] = (int)(rec & 0xffffu);
  }
}

// ---------------- gather-reduce + fused tanh (fp16 Y rows) ----------------
// one 64-lane wave per node; one uint (=half2) per lane covers the 256B row; unroll 8
__global__ __launch_bounds__(256) void gather_kernel(
    const unsigned* __restrict__ Yh, const int* __restrict__ sorted_src,
    const int* __restrict__ row_start, const int* __restrict__ counts_d,
    const float* __restrict__ norm, const float* __restrict__ b,
    float* __restrict__ out, int n_nodes) {
  int node = blockIdx.x * 4 + (threadIdx.x >> 6);
  if (node >= n_nodes) return;
  int lane = threadIdx.x & 63;
  int beg = row_start[node];
  int cnt = counts_d[node];
  float accx = 0.f, accy = 0.f;
  int i = beg, end = beg + cnt;
  for (; i + 8 <= end; i += 8) {
    int s0 = sorted_src[i + 0];
    int s1 = sorted_src[i + 1];
    int s2 = sorted_src[i + 2];
    int s3 = sorted_src[i + 3];
    int s4 = sorted_src[i + 4];
    int s5 = sorted_src[i + 5];
    int s6 = sorted_src[i + 6];
    int s7 = sorted_src[i + 7];
    unsigned u0 = Yh[(size_t)s0 * 64 + lane];
    unsigned u1 = Yh[(size_t)s1 * 64 + lane];
    unsigned u2 = Yh[(size_t)s2 * 64 + lane];
    unsigned u3 = Yh[(size_t)s3 * 64 + lane];
    unsigned u4 = Yh[(size_t)s4 * 64 + lane];
    unsigned u5 = Yh[(size_t)s5 * 64 + lane];
    unsigned u6 = Yh[(size_t)s6 * 64 + lane];
    unsigned u7 = Yh[(size_t)s7 * 64 + lane];
    float2 v0 = __half22float2(*reinterpret_cast<__half2*>(&u0));
    float2 v1 = __half22float2(*reinterpret_cast<__half2*>(&u1));
    float2 v2 = __half22float2(*reinterpret_cast<__half2*>(&u2));
    float2 v3 = __half22float2(*reinterpret_cast<__half2*>(&u3));
    float2 v4 = __half22float2(*reinterpret_cast<__half2*>(&u4));
    float2 v5 = __half22float2(*reinterpret_cast<__half2*>(&u5));
    float2 v6 = __half22float2(*reinterpret_cast<__half2*>(&u6));
    float2 v7 = __half22float2(*reinterpret_cast<__half2*>(&u7));
    accx += (v0.x + v1.x) + (v2.x + v3.x) + ((v4.x + v5.x) + (v6.x + v7.x));
    accy += (v0.y + v1.y) + (v2.y + v3.y) + ((v4.y + v5.y) + (v6.y + v7.y));
  }
  for (; i < end; ++i) {
    int s = sorted_src[i];
    unsigned u = Yh[(size_t)s * 64 + lane];
    float2 v = __half22float2(*reinterpret_cast<__half2*>(&u));
    accx += v.x;
    accy += v.y;
  }
  float nm = norm[node];
  float2 bb = ((const float2*)b)[lane];
  float2 h;
  h.x = tanhf(accx * nm + bb.x);
  h.y = tanhf(accy * nm + bb.y);
  ((float2*)out)[(size_t)node * 64 + lane] = h;
}

extern "C" void kernel_launch(void* const* d_in, const int* in_sizes, int n_in,
                              void* d_out, int out_size, void* d_ws, size_t ws_size,
                              hipStream_t stream) {
  const float* feat = (const float*)d_in[0];   // [N,128]
  const float* norm = (const float*)d_in[1];   // [N,1]
  const float* W    = (const float*)d_in[2];   // [128,128]
  const float* b    = (const float*)d_in[3];   // [128]
  const int* src    = (const int*)d_in[4];     // [E]
  const int* dst    = (const int*)d_in[5];     // [E]
  float* out        = (float*)d_out;           // [N,128]

  const int n_nodes = in_sizes[1];
  const int n_edges = in_sizes[4];
  const int nb = (n_nodes + BNODES - 1) / BNODES;   // 391

  // workspace layout
  char* base = (char*)d_ws;
  unsigned* Yh = (unsigned*)base;                   // N*64 uints (fp16-packed rows)
  size_t off = (size_t)n_nodes * 64 * sizeof(unsigned);
  off = (off + 255) & ~(size_t)255;
  int* counts = (int*)(base + off); off += (size_t)nb * 4;     // coarse bucket counts
  off = (off + 255) & ~(size_t)255;
  int* bstart = (int*)(base + off); off += (size_t)nb * 4;
  off = (off + 255) & ~(size_t)255;
  int* cursor = (int*)(base + off); off += (size_t)nb * 4;
  off = (off + 255) & ~(size_t)255;
  unsigned* recs = (unsigned*)(base + off); off += (size_t)n_edges * 4;
  off = (off + 255) & ~(size_t)255;
  int* sorted_src = (int*)(base + off); off += (size_t)n_edges * 4;
  off = (off + 255) & ~(size_t)255;
  int* row_start = (int*)(base + off); off += (size_t)n_nodes * 4;
  off = (off + 255) & ~(size_t)255;
  int* counts_d = (int*)(base + off); off += (size_t)n_nodes * 4;

  // 1) Yh = fp16( norm * (feat @ W^T) )
  int gblocks = (n_nodes + 63) / 64;
  gemm_kernel<<<gblocks, 256, 0, stream>>>(feat, norm, W, Yh, n_nodes);

  // 2) coarse bucket histogram
  hipMemsetAsync(counts, 0, (size_t)nb * sizeof(int), stream);
  hist_kernel<<<256, 256, 0, stream>>>(dst, counts, n_edges, nb);

  // 3) scan -> bucket starts + cursors
  scan_kernel<<<1, 512, 0, stream>>>(counts, bstart, cursor, nb);

  // 4) partition edges into dst-buckets (dense writes)
  int chunks = (n_edges + CHUNK - 1) / CHUNK;
  partition_kernel<<<chunks, 256, 0, stream>>>(src, dst, cursor, recs, n_edges, nb);

  // 5) per-bucket counting sort -> per-node CSR (bucket-local traffic only)
  localize_kernel<<<nb, 256, 0, stream>>>(recs, bstart, counts, sorted_src,
                                          row_start, counts_d, n_nodes);

  // 6) wave-per-node gather-reduce + fused tanh(norm*agg + b)
  int nblocks = (n_nodes + 3) / 4;
  gather_kernel<<<nblocks, 256, 0, stream>>>(Yh, sorted_src, row_start, counts_d,
                                             norm, b, out, n_nodes);
}

// Round 10
// 107.903 us; speedup vs baseline: 7.0101x; 1.0554x over previous
//
#include <hip/hip_runtime.h>
#include <hip/hip_fp16.h>
#include <math.h>

#define NBITS 7            // log2(nodes per bucket)
#define BNODES 128         // nodes per bucket
#define CHUNK 2048         // edges per partition block
#define BSHIFT 12          // fixed bucket stride 4096 records (mean ~2046, +45 sigma)

__device__ __forceinline__ unsigned hpack(float a, float b) {
  __half2 h = __floats2half2_rn(a, b);
  return *reinterpret_cast<unsigned*>(&h);
}

// ---------------- GEMM: Yh[n] = fp16( norm[n] * (feat[n] @ W^T) ) ----------------
// Yh row = 64 uints; uint j holds features (2j, 2j+1) as half2.
__global__ __launch_bounds__(256) void gemm_kernel(
    const float* __restrict__ feat, const float* __restrict__ norm,
    const float* __restrict__ W, unsigned* __restrict__ Yh, int n_nodes) {
  __shared__ float sWt[64][132];   // [f][o] transposed
  __shared__ float sA[64][68];     // [node][f]
  const int t = threadIdx.x;
  const int node0 = blockIdx.x * 64;
  const int og = t & 31;           // outputs og*4 .. og*4+3
  const int ng = t >> 5;

  float acc[8][4];
#pragma unroll
  for (int j = 0; j < 8; ++j)
#pragma unroll
    for (int k = 0; k < 4; ++k) acc[j][k] = 0.f;

  for (int half = 0; half < 2; ++half) {
    __syncthreads();
#pragma unroll
    for (int k = 0; k < 8; ++k) {
      int e4 = k * 256 + t;
      int oo = e4 >> 4;
      int f4 = (e4 & 15) * 4;
      float4 w = *(const float4*)&W[oo * 128 + half * 64 + f4];
      sWt[f4 + 0][oo] = w.x; sWt[f4 + 1][oo] = w.y;
      sWt[f4 + 2][oo] = w.z; sWt[f4 + 3][oo] = w.w;
    }
#pragma unroll
    for (int k = 0; k < 4; ++k) {
      int e4 = k * 256 + t;
      int nn = e4 >> 4;
      int f4 = (e4 & 15) * 4;
      int node = node0 + nn;
      float4 a = (node < n_nodes)
                     ? *(const float4*)&feat[(size_t)node * 128 + half * 64 + f4]
                     : make_float4(0.f, 0.f, 0.f, 0.f);
      *(float4*)&sA[nn][f4] = a;
    }
    __syncthreads();
#pragma unroll 4
    for (int f = 0; f < 64; ++f) {
      float4 w = *(const float4*)&sWt[f][og * 4];
#pragma unroll
      for (int j = 0; j < 8; ++j) {
        float a = sA[ng * 8 + j][f];
        acc[j][0] += a * w.x; acc[j][1] += a * w.y;
        acc[j][2] += a * w.z; acc[j][3] += a * w.w;
      }
    }
  }
#pragma unroll
  for (int j = 0; j < 8; ++j) {
    int node = node0 + ng * 8 + j;
    if (node < n_nodes) {
      float nm = norm[node];
      uint2 u;
      u.x = hpack(acc[j][0] * nm, acc[j][1] * nm);   // features og*4, og*4+1
      u.y = hpack(acc[j][2] * nm, acc[j][3] * nm);   // features og*4+2, og*4+3
      ((uint2*)Yh)[(size_t)node * 32 + og] = u;
    }
  }
}

// ---------------- partition: LDS counting-sort per chunk -> fixed-stride buckets ----------------
// record = src | (dst << 16)   (requires n_nodes <= 65536)
// bucket b occupies recs[b<<BSHIFT .. ]; cursor[b] counts entries (init 0).
__global__ __launch_bounds__(256) void partition_kernel(
    const int* __restrict__ src, const int* __restrict__ dst,
    int* __restrict__ cursor, unsigned* __restrict__ recs, int n_edges, int nb) {
  __shared__ int lcount[512];
  __shared__ int lbase[512];
  __shared__ int gbase[512];
  __shared__ int aux[256];
  __shared__ unsigned stage[CHUNK];
  __shared__ int s_total;
  const int t = threadIdx.x;
  const int cbase = blockIdx.x * CHUNK;

  lcount[t] = 0; lcount[t + 256] = 0;
  __syncthreads();

  int es[8], ed[8], rk[8];
#pragma unroll
  for (int q = 0; q < 2; ++q) {
    int i4 = (cbase >> 2) + q * 256 + t;
    int e0 = i4 << 2;
    int4 sv, dv;
    if (e0 + 3 < n_edges) {
      sv = ((const int4*)src)[i4];
      dv = ((const int4*)dst)[i4];
    } else {
      sv.x = (e0 + 0 < n_edges) ? src[e0 + 0] : 0;
      sv.y = (e0 + 1 < n_edges) ? src[e0 + 1] : 0;
      sv.z = (e0 + 2 < n_edges) ? src[e0 + 2] : 0;
      sv.w = 0;
      dv.x = (e0 + 0 < n_edges) ? dst[e0 + 0] : -1;
      dv.y = (e0 + 1 < n_edges) ? dst[e0 + 1] : -1;
      dv.z = (e0 + 2 < n_edges) ? dst[e0 + 2] : -1;
      dv.w = -1;
    }
    es[q * 4 + 0] = sv.x; ed[q * 4 + 0] = dv.x;
    es[q * 4 + 1] = sv.y; ed[q * 4 + 1] = dv.y;
    es[q * 4 + 2] = sv.z; ed[q * 4 + 2] = dv.z;
    es[q * 4 + 3] = sv.w; ed[q * 4 + 3] = dv.w;
  }
#pragma unroll
  for (int k = 0; k < 8; ++k)
    rk[k] = (ed[k] >= 0) ? atomicAdd(&lcount[ed[k] >> NBITS], 1) : 0;
  __syncthreads();

  // block scan of lcount[512] -> lbase (exclusive)
  int a = lcount[2 * t] + lcount[2 * t + 1];
  aux[t] = a;
  __syncthreads();
  for (int off = 1; off < 256; off <<= 1) {
    int u = (t >= off) ? aux[t - off] : 0;
    __syncthreads();
    aux[t] += u;
    __syncthreads();
  }
  int ex = aux[t] - a;
  lbase[2 * t] = ex;
  lbase[2 * t + 1] = ex + lcount[2 * t];
  if (t == 255) s_total = aux[255];
  __syncthreads();

  // reserve ranges in fixed-stride buckets
  for (int b = t; b < nb; b += 256)
    gbase[b] = (lcount[b] > 0) ? ((b << BSHIFT) + atomicAdd(&cursor[b], lcount[b]))
                               : 0;
  __syncthreads();

  // scatter into LDS stage (bucket-sorted within chunk)
#pragma unroll
  for (int k = 0; k < 8; ++k) {
    if (ed[k] >= 0) {
      int b = ed[k] >> NBITS;
      stage[lbase[b] + rk[k]] = (unsigned)es[k] | ((unsigned)ed[k] << 16);
    }
  }
  __syncthreads();

  // dense copy out: consecutive r -> consecutive global positions per bucket
  int total = s_total;
  for (int r = t; r < total; r += 256) {
    unsigned rec = stage[r];
    int b = (int)(rec >> (16 + NBITS));
    recs[gbase[b] + (r - lbase[b])] = rec;
  }
}

// ---------------- localize: per-bucket counting sort by node -> per-node CSR ----------------
__global__ __launch_bounds__(256) void localize_kernel(
    const unsigned* __restrict__ recs, const int* __restrict__ cursor,
    int* __restrict__ sorted_src, int* __restrict__ row_start,
    int* __restrict__ counts_d, int n_nodes) {
  __shared__ int lc[BNODES];
  __shared__ int ls[BNODES];
  __shared__ int cur[BNODES];
  const int t = threadIdx.x;
  const int b = blockIdx.x;
  const int cbeg = b << BSHIFT;
  const int cnt = cursor[b];

  if (t < BNODES) lc[t] = 0;
  __syncthreads();
  for (int i = t; i < cnt; i += 256) {
    unsigned rec = recs[cbeg + i];
    atomicAdd(&lc[(rec >> 16) & (BNODES - 1)], 1);
  }
  __syncthreads();
  if (t < BNODES) ls[t] = lc[t];
  __syncthreads();
  for (int off = 1; off < BNODES; off <<= 1) {
    int u = (t < BNODES && t >= off) ? ls[t - off] : 0;
    __syncthreads();
    if (t < BNODES) ls[t] += u;
    __syncthreads();
  }
  if (t < BNODES) {
    int ex = ls[t] - lc[t];       // exclusive prefix within bucket
    cur[t] = ex;
    int node = (b << NBITS) + t;
    if (node < n_nodes) {
      counts_d[node] = lc[t];
      row_start[node] = cbeg + ex;
    }
  }
  __syncthreads();
  for (int i = t; i < cnt; i += 256) {
    unsigned rec = recs[cbeg + i];
    int nl = (rec >> 16) & (BNODES - 1);
    int p = atomicAdd(&cur[nl], 1);
    sorted_src[cbeg + p] = (int)(rec & 0xffffu);
  }
}

// ---------------- gather-reduce + fused tanh (fp16 Y rows) ----------------
// one 64-lane wave per node; one uint (=half2) per lane covers the 256B row; unroll 8
__global__ __launch_bounds__(256) void gather_kernel(
    const unsigned* __restrict__ Yh, const int* __restrict__ sorted_src,
    const int* __restrict__ row_start, const int* __restrict__ counts_d,
    const float* __restrict__ norm, const float* __restrict__ b,
    float* __restrict__ out, int n_nodes) {
  int node = blockIdx.x * 4 + (threadIdx.x >> 6);
  if (node >= n_nodes) return;
  int lane = threadIdx.x & 63;
  int beg = row_start[node];
  int cnt = counts_d[node];
  float accx = 0.f, accy = 0.f;
  int i = beg, end = beg + cnt;
  for (; i + 8 <= end; i += 8) {
    int s0 = sorted_src[i + 0];
    int s1 = sorted_src[i + 1];
    int s2 = sorted_src[i + 2];
    int s3 = sorted_src[i + 3];
    int s4 = sorted_src[i + 4];
    int s5 = sorted_src[i + 5];
    int s6 = sorted_src[i + 6];
    int s7 = sorted_src[i + 7];
    unsigned u0 = Yh[(size_t)s0 * 64 + lane];
    unsigned u1 = Yh[(size_t)s1 * 64 + lane];
    unsigned u2 = Yh[(size_t)s2 * 64 + lane];
    unsigned u3 = Yh[(size_t)s3 * 64 + lane];
    unsigned u4 = Yh[(size_t)s4 * 64 + lane];
    unsigned u5 = Yh[(size_t)s5 * 64 + lane];
    unsigned u6 = Yh[(size_t)s6 * 64 + lane];
    unsigned u7 = Yh[(size_t)s7 * 64 + lane];
    float2 v0 = __half22float2(*reinterpret_cast<__half2*>(&u0));
    float2 v1 = __half22float2(*reinterpret_cast<__half2*>(&u1));
    float2 v2 = __half22float2(*reinterpret_cast<__half2*>(&u2));
    float2 v3 = __half22float2(*reinterpret_cast<__half2*>(&u3));
    float2 v4 = __half22float2(*reinterpret_cast<__half2*>(&u4));
    float2 v5 = __half22float2(*reinterpret_cast<__half2*>(&u5));
    float2 v6 = __half22float2(*reinterpret_cast<__half2*>(&u6));
    float2 v7 = __half22float2(*reinterpret_cast<__half2*>(&u7));
    accx += (v0.x + v1.x) + (v2.x + v3.x) + ((v4.x + v5.x) + (v6.x + v7.x));
    accy += (v0.y + v1.y) + (v2.y + v3.y) + ((v4.y + v5.y) + (v6.y + v7.y));
  }
  for (; i < end; ++i) {
    int s = sorted_src[i];
    unsigned u = Yh[(size_t)s * 64 + lane];
    float2 v = __half22float2(*reinterpret_cast<__half2*>(&u));
    accx += v.x;
    accy += v.y;
  }
  float nm = norm[node];
  float2 bb = ((const float2*)b)[lane];
  float2 h;
  h.x = tanhf(accx * nm + bb.x);
  h.y = tanhf(accy * nm + bb.y);
  ((float2*)out)[(size_t)node * 64 + lane] = h;
}

extern "C" void kernel_launch(void* const* d_in, const int* in_sizes, int n_in,
                              void* d_out, int out_size, void* d_ws, size_t ws_size,
                              hipStream_t stream) {
  const float* feat = (const float*)d_in[0];   // [N,128]
  const float* norm = (const float*)d_in[1];   // [N,1]
  const float* W    = (const float*)d_in[2];   // [128,128]
  const float* b    = (const float*)d_in[3];   // [128]
  const int* src    = (const int*)d_in[4];     // [E]
  const int* dst    = (const int*)d_in[5];     // [E]
  float* out        = (float*)d_out;           // [N,128]

  const int n_nodes = in_sizes[1];
  const int n_edges = in_sizes[4];
  const int nb = (n_nodes + BNODES - 1) / BNODES;   // 391

  // workspace layout
  char* base = (char*)d_ws;
  unsigned* Yh = (unsigned*)base;                   // N*64 uints (fp16-packed rows)
  size_t off = (size_t)n_nodes * 64 * sizeof(unsigned);
  off = (off + 255) & ~(size_t)255;
  int* cursor = (int*)(base + off); off += (size_t)nb * 4;
  off = (off + 255) & ~(size_t)255;
  unsigned* recs = (unsigned*)(base + off); off += ((size_t)nb << BSHIFT) * 4;
  off = (off + 255) & ~(size_t)255;
  int* sorted_src = (int*)(base + off); off += ((size_t)nb << BSHIFT) * 4;
  off = (off + 255) & ~(size_t)255;
  int* row_start = (int*)(base + off); off += (size_t)n_nodes * 4;
  off = (off + 255) & ~(size_t)255;
  int* counts_d = (int*)(base + off); off += (size_t)n_nodes * 4;

  // 0) zero bucket cursors
  hipMemsetAsync(cursor, 0, (size_t)nb * sizeof(int), stream);

  // 1) Yh = fp16( norm * (feat @ W^T) )
  int gblocks = (n_nodes + 63) / 64;
  gemm_kernel<<<gblocks, 256, 0, stream>>>(feat, norm, W, Yh, n_nodes);

  // 2) partition edges into fixed-stride dst-buckets (dense writes)
  int chunks = (n_edges + CHUNK - 1) / CHUNK;
  partition_kernel<<<chunks, 256, 0, stream>>>(src, dst, cursor, recs, n_edges, nb);

  // 3) per-bucket counting sort -> per-node CSR (bucket-local traffic only)
  localize_kernel<<<nb, 256, 0, stream>>>(recs, cursor, sorted_src,
                                          row_start, counts_d, n_nodes);

  // 4) wave-per-node gather-reduce + fused tanh(norm*agg + b)
  int nblocks = (n_nodes + 3) / 4;
  gather_kernel<<<nblocks, 256, 0, stream>>>(Yh, sorted_src, row_start, counts_d,
                                             norm, b, out, n_nodes);
}

// Round 11
// 106.249 us; speedup vs baseline: 7.1192x; 1.0156x over previous
//
#include <hip/hip_runtime.h>
#include <hip/hip_fp16.h>
#include <math.h>

#define NBITS 7            // log2(nodes per bucket)
#define BNODES 128         // nodes per bucket
#define CHUNK 2048         // edges per partition block
#define BSHIFT 12          // fixed bucket stride 4096 records (mean ~2046, +45 sigma)

__device__ __forceinline__ unsigned hpack(float a, float b) {
  __half2 h = __floats2half2_rn(a, b);
  return *reinterpret_cast<unsigned*>(&h);
}

// ---------------- GEMM: Yh[n] = fp16( norm[n] * (feat[n] @ W^T) ) ----------------
// 128x128 tile, 256 threads, thread = 8 nodes x 8 outputs, K-blocked float4 LDS reads.
// Thread (og=t&15, ng=t>>4): outputs {og*4..+3, og*4+64..+67}, nodes {ng+16j}.
__global__ __launch_bounds__(256) void gemm_kernel(
    const float* __restrict__ feat, const float* __restrict__ norm,
    const float* __restrict__ W, unsigned* __restrict__ Yh, int n_nodes) {
  __shared__ float sWt[64][132];   // [f][o] transposed; 528B row (16B aligned)
  __shared__ float sA[128][68];    // [node][f]; 272B row (16B aligned)
  const int t = threadIdx.x;
  const int node0 = blockIdx.x * 128;
  const int og = t & 15;
  const int ng = t >> 4;

  float acc[8][8];                 // [j][i]: i 0..3 -> og*4+i, 4..7 -> og*4+64+i
#pragma unroll
  for (int j = 0; j < 8; ++j)
#pragma unroll
    for (int i = 0; i < 8; ++i) acc[j][i] = 0.f;

  for (int half = 0; half < 2; ++half) {
    __syncthreads();
    // stage W[:, half*64 .. +64] transposed: 128 outs x 64 f = 2048 float4
#pragma unroll
    for (int k = 0; k < 8; ++k) {
      int e4 = k * 256 + t;        // 0..2047
      int oo = e4 >> 4;            // 0..127
      int f4 = (e4 & 15) * 4;
      float4 w = *(const float4*)&W[oo * 128 + half * 64 + f4];
      sWt[f4 + 0][oo] = w.x; sWt[f4 + 1][oo] = w.y;
      sWt[f4 + 2][oo] = w.z; sWt[f4 + 3][oo] = w.w;
    }
    // stage feat: 128 nodes x 64 f = 2048 float4
#pragma unroll
    for (int k = 0; k < 8; ++k) {
      int e4 = k * 256 + t;        // 0..2047
      int nn = e4 >> 4;            // 0..127
      int f4 = (e4 & 15) * 4;
      int node = node0 + nn;
      float4 a = (node < n_nodes)
                     ? *(const float4*)&feat[(size_t)node * 128 + half * 64 + f4]
                     : make_float4(0.f, 0.f, 0.f, 0.f);
      *(float4*)&sA[nn][f4] = a;
    }
    __syncthreads();
#pragma unroll 4
    for (int f4 = 0; f4 < 64; f4 += 4) {
      float4 a[8];
#pragma unroll
      for (int j = 0; j < 8; ++j)
        a[j] = *(const float4*)&sA[ng + 16 * j][f4];
      float4 w1[4], w2[4];
#pragma unroll
      for (int k = 0; k < 4; ++k) {
        w1[k] = *(const float4*)&sWt[f4 + k][og * 4];
        w2[k] = *(const float4*)&sWt[f4 + k][og * 4 + 64];
      }
#pragma unroll
      for (int j = 0; j < 8; ++j) {
#pragma unroll
        for (int k = 0; k < 4; ++k) {
          float av = (&a[j].x)[k];
          acc[j][0] += av * w1[k].x; acc[j][1] += av * w1[k].y;
          acc[j][2] += av * w1[k].z; acc[j][3] += av * w1[k].w;
          acc[j][4] += av * w2[k].x; acc[j][5] += av * w2[k].y;
          acc[j][6] += av * w2[k].z; acc[j][7] += av * w2[k].w;
        }
      }
    }
  }
  // epilogue: fp16-pack with norm scaling
#pragma unroll
  for (int j = 0; j < 8; ++j) {
    int node = node0 + ng + 16 * j;
    if (node < n_nodes) {
      float nm = norm[node];
      uint2 ua, ub;
      ua.x = hpack(acc[j][0] * nm, acc[j][1] * nm);
      ua.y = hpack(acc[j][2] * nm, acc[j][3] * nm);
      ub.x = hpack(acc[j][4] * nm, acc[j][5] * nm);
      ub.y = hpack(acc[j][6] * nm, acc[j][7] * nm);
      ((uint2*)Yh)[(size_t)node * 32 + og] = ua;        // uints og*2, og*2+1
      ((uint2*)Yh)[(size_t)node * 32 + og + 16] = ub;   // uints og*2+32, og*2+33
    }
  }
}

// ---------------- partition: LDS counting-sort per chunk -> fixed-stride buckets ----------------
// record = src | (dst << 16)   (requires n_nodes <= 65536)
// bucket b occupies recs[b<<BSHIFT .. ]; cursor[b] counts entries (init 0).
__global__ __launch_bounds__(256) void partition_kernel(
    const int* __restrict__ src, const int* __restrict__ dst,
    int* __restrict__ cursor, unsigned* __restrict__ recs, int n_edges, int nb) {
  __shared__ int lcount[512];
  __shared__ int lbase[512];
  __shared__ int gbase[512];
  __shared__ int aux[256];
  __shared__ unsigned stage[CHUNK];
  __shared__ int s_total;
  const int t = threadIdx.x;
  const int cbase = blockIdx.x * CHUNK;

  lcount[t] = 0; lcount[t + 256] = 0;
  __syncthreads();

  int es[8], ed[8], rk[8];
#pragma unroll
  for (int q = 0; q < 2; ++q) {
    int i4 = (cbase >> 2) + q * 256 + t;
    int e0 = i4 << 2;
    int4 sv, dv;
    if (e0 + 3 < n_edges) {
      sv = ((const int4*)src)[i4];
      dv = ((const int4*)dst)[i4];
    } else {
      sv.x = (e0 + 0 < n_edges) ? src[e0 + 0] : 0;
      sv.y = (e0 + 1 < n_edges) ? src[e0 + 1] : 0;
      sv.z = (e0 + 2 < n_edges) ? src[e0 + 2] : 0;
      sv.w = 0;
      dv.x = (e0 + 0 < n_edges) ? dst[e0 + 0] : -1;
      dv.y = (e0 + 1 < n_edges) ? dst[e0 + 1] : -1;
      dv.z = (e0 + 2 < n_edges) ? dst[e0 + 2] : -1;
      dv.w = -1;
    }
    es[q * 4 + 0] = sv.x; ed[q * 4 + 0] = dv.x;
    es[q * 4 + 1] = sv.y; ed[q * 4 + 1] = dv.y;
    es[q * 4 + 2] = sv.z; ed[q * 4 + 2] = dv.z;
    es[q * 4 + 3] = sv.w; ed[q * 4 + 3] = dv.w;
  }
#pragma unroll
  for (int k = 0; k < 8; ++k)
    rk[k] = (ed[k] >= 0) ? atomicAdd(&lcount[ed[k] >> NBITS], 1) : 0;
  __syncthreads();

  // block scan of lcount[512] -> lbase (exclusive)
  int a = lcount[2 * t] + lcount[2 * t + 1];
  aux[t] = a;
  __syncthreads();
  for (int off = 1; off < 256; off <<= 1) {
    int u = (t >= off) ? aux[t - off] : 0;
    __syncthreads();
    aux[t] += u;
    __syncthreads();
  }
  int ex = aux[t] - a;
  lbase[2 * t] = ex;
  lbase[2 * t + 1] = ex + lcount[2 * t];
  if (t == 255) s_total = aux[255];
  __syncthreads();

  // reserve ranges in fixed-stride buckets
  for (int b = t; b < nb; b += 256)
    gbase[b] = (lcount[b] > 0) ? ((b << BSHIFT) + atomicAdd(&cursor[b], lcount[b]))
                               : 0;
  __syncthreads();

  // scatter into LDS stage (bucket-sorted within chunk)
#pragma unroll
  for (int k = 0; k < 8; ++k) {
    if (ed[k] >= 0) {
      int b = ed[k] >> NBITS;
      stage[lbase[b] + rk[k]] = (unsigned)es[k] | ((unsigned)ed[k] << 16);
    }
  }
  __syncthreads();

  // dense copy out: consecutive r -> consecutive global positions per bucket
  int total = s_total;
  for (int r = t; r < total; r += 256) {
    unsigned rec = stage[r];
    int b = (int)(rec >> (16 + NBITS));
    recs[gbase[b] + (r - lbase[b])] = rec;
  }
}

// ---------------- localize: per-bucket counting sort by node -> per-node CSR ----------------
__global__ __launch_bounds__(256) void localize_kernel(
    const unsigned* __restrict__ recs, const int* __restrict__ cursor,
    int* __restrict__ sorted_src, int* __restrict__ row_start,
    int* __restrict__ counts_d, int n_nodes) {
  __shared__ int lc[BNODES];
  __shared__ int ls[BNODES];
  __shared__ int cur[BNODES];
  const int t = threadIdx.x;
  const int b = blockIdx.x;
  const int cbeg = b << BSHIFT;
  const int cnt = cursor[b];

  if (t < BNODES) lc[t] = 0;
  __syncthreads();
  for (int i = t; i < cnt; i += 256) {
    unsigned rec = recs[cbeg + i];
    atomicAdd(&lc[(rec >> 16) & (BNODES - 1)], 1);
  }
  __syncthreads();
  if (t < BNODES) ls[t] = lc[t];
  __syncthreads();
  for (int off = 1; off < BNODES; off <<= 1) {
    int u = (t < BNODES && t >= off) ? ls[t - off] : 0;
    __syncthreads();
    if (t < BNODES) ls[t] += u;
    __syncthreads();
  }
  if (t < BNODES) {
    int ex = ls[t] - lc[t];       // exclusive prefix within bucket
    cur[t] = ex;
    int node = (b << NBITS) + t;
    if (node < n_nodes) {
      counts_d[node] = lc[t];
      row_start[node] = cbeg + ex;
    }
  }
  __syncthreads();
  for (int i = t; i < cnt; i += 256) {
    unsigned rec = recs[cbeg + i];
    int nl = (rec >> 16) & (BNODES - 1);
    int p = atomicAdd(&cur[nl], 1);
    sorted_src[cbeg + p] = (int)(rec & 0xffffu);
  }
}

// ---------------- gather-reduce + fused tanh (fp16 Y rows) ----------------
// one 64-lane wave per node; one uint (=half2) per lane covers the 256B row; unroll 8
__global__ __launch_bounds__(256) void gather_kernel(
    const unsigned* __restrict__ Yh, const int* __restrict__ sorted_src,
    const int* __restrict__ row_start, const int* __restrict__ counts_d,
    const float* __restrict__ norm, const float* __restrict__ b,
    float* __restrict__ out, int n_nodes) {
  int node = blockIdx.x * 4 + (threadIdx.x >> 6);
  if (node >= n_nodes) return;
  int lane = threadIdx.x & 63;
  int beg = row_start[node];
  int cnt = counts_d[node];
  float accx = 0.f, accy = 0.f;
  int i = beg, end = beg + cnt;
  for (; i + 8 <= end; i += 8) {
    int s0 = sorted_src[i + 0];
    int s1 = sorted_src[i + 1];
    int s2 = sorted_src[i + 2];
    int s3 = sorted_src[i + 3];
    int s4 = sorted_src[i + 4];
    int s5 = sorted_src[i + 5];
    int s6 = sorted_src[i + 6];
    int s7 = sorted_src[i + 7];
    unsigned u0 = Yh[(size_t)s0 * 64 + lane];
    unsigned u1 = Yh[(size_t)s1 * 64 + lane];
    unsigned u2 = Yh[(size_t)s2 * 64 + lane];
    unsigned u3 = Yh[(size_t)s3 * 64 + lane];
    unsigned u4 = Yh[(size_t)s4 * 64 + lane];
    unsigned u5 = Yh[(size_t)s5 * 64 + lane];
    unsigned u6 = Yh[(size_t)s6 * 64 + lane];
    unsigned u7 = Yh[(size_t)s7 * 64 + lane];
    float2 v0 = __half22float2(*reinterpret_cast<__half2*>(&u0));
    float2 v1 = __half22float2(*reinterpret_cast<__half2*>(&u1));
    float2 v2 = __half22float2(*reinterpret_cast<__half2*>(&u2));
    float2 v3 = __half22float2(*reinterpret_cast<__half2*>(&u3));
    float2 v4 = __half22float2(*reinterpret_cast<__half2*>(&u4));
    float2 v5 = __half22float2(*reinterpret_cast<__half2*>(&u5));
    float2 v6 = __half22float2(*reinterpret_cast<__half2*>(&u6));
    float2 v7 = __half22float2(*reinterpret_cast<__half2*>(&u7));
    accx += (v0.x + v1.x) + (v2.x + v3.x) + ((v4.x + v5.x) + (v6.x + v7.x));
    accy += (v0.y + v1.y) + (v2.y + v3.y) + ((v4.y + v5.y) + (v6.y + v7.y));
  }
  for (; i < end; ++i) {
    int s = sorted_src[i];
    unsigned u = Yh[(size_t)s * 64 + lane];
    float2 v = __half22float2(*reinterpret_cast<__half2*>(&u));
    accx += v.x;
    accy += v.y;
  }
  float nm = norm[node];
  float2 bb = ((const float2*)b)[lane];
  float2 h;
  h.x = tanhf(accx * nm + bb.x);
  h.y = tanhf(accy * nm + bb.y);
  ((float2*)out)[(size_t)node * 64 + lane] = h;
}

extern "C" void kernel_launch(void* const* d_in, const int* in_sizes, int n_in,
                              void* d_out, int out_size, void* d_ws, size_t ws_size,
                              hipStream_t stream) {
  const float* feat = (const float*)d_in[0];   // [N,128]
  const float* norm = (const float*)d_in[1];   // [N,1]
  const float* W    = (const float*)d_in[2];   // [128,128]
  const float* b    = (const float*)d_in[3];   // [128]
  const int* src    = (const int*)d_in[4];     // [E]
  const int* dst    = (const int*)d_in[5];     // [E]
  float* out        = (float*)d_out;           // [N,128]

  const int n_nodes = in_sizes[1];
  const int n_edges = in_sizes[4];
  const int nb = (n_nodes + BNODES - 1) / BNODES;   // 391

  // workspace layout
  char* base = (char*)d_ws;
  unsigned* Yh = (unsigned*)base;                   // N*64 uints (fp16-packed rows)
  size_t off = (size_t)n_nodes * 64 * sizeof(unsigned);
  off = (off + 255) & ~(size_t)255;
  int* cursor = (int*)(base + off); off += (size_t)nb * 4;
  off = (off + 255) & ~(size_t)255;
  unsigned* recs = (unsigned*)(base + off); off += ((size_t)nb << BSHIFT) * 4;
  off = (off + 255) & ~(size_t)255;
  int* sorted_src = (int*)(base + off); off += ((size_t)nb << BSHIFT) * 4;
  off = (off + 255) & ~(size_t)255;
  int* row_start = (int*)(base + off); off += (size_t)n_nodes * 4;
  off = (off + 255) & ~(size_t)255;
  int* counts_d = (int*)(base + off); off += (size_t)n_nodes * 4;

  // 0) zero bucket cursors
  hipMemsetAsync(cursor, 0, (size_t)nb * sizeof(int), stream);

  // 1) Yh = fp16( norm * (feat @ W^T) )
  int gblocks = (n_nodes + 127) / 128;
  gemm_kernel<<<gblocks, 256, 0, stream>>>(feat, norm, W, Yh, n_nodes);

  // 2) partition edges into fixed-stride dst-buckets (dense writes)
  int chunks = (n_edges + CHUNK - 1) / CHUNK;
  partition_kernel<<<chunks, 256, 0, stream>>>(src, dst, cursor, recs, n_edges, nb);

  // 3) per-bucket counting sort -> per-node CSR (bucket-local traffic only)
  localize_kernel<<<nb, 256, 0, stream>>>(recs, cursor, sorted_src,
                                          row_start, counts_d, n_nodes);

  // 4) wave-per-node gather-reduce + fused tanh(norm*agg + b)
  int nblocks = (n_nodes + 3) / 4;
  gather_kernel<<<nblocks, 256, 0, stream>>>(Yh, sorted_src, row_start, counts_d,
                                             norm, b, out, n_nodes);
}

// Round 12
// 91.144 us; speedup vs baseline: 8.2990x; 1.1657x over previous
//
#include <hip/hip_runtime.h>
#include <hip/hip_fp16.h>
#include <math.h>

#define NBITS 7            // log2(nodes per bucket)
#define BNODES 128         // nodes per bucket
#define CHUNK 4096         // edges per partition block
#define BSHIFT 12          // fixed bucket stride 4096 records (mean ~2046, +45 sigma)

__device__ __forceinline__ unsigned hpack(float a, float b) {
  __half2 h = __floats2half2_rn(a, b);
  return *reinterpret_cast<unsigned*>(&h);
}

// ---------------- GEMM: Yh[n] = fp16( norm[n] * (feat[n] @ W^T) ) ----------------
// 128x128 tile, 256 threads, thread = 8 nodes x 8 outputs, K-blocked float4 LDS reads.
// Block 0 also zeroes the partition cursors (gemm precedes partition in-stream).
__global__ __launch_bounds__(256) void gemm_kernel(
    const float* __restrict__ feat, const float* __restrict__ norm,
    const float* __restrict__ W, unsigned* __restrict__ Yh, int n_nodes,
    int* __restrict__ cursor, int nb) {
  __shared__ float sWt[64][132];   // [f][o] transposed
  __shared__ float sA[128][68];    // [node][f]
  const int t = threadIdx.x;
  const int node0 = blockIdx.x * 128;
  const int og = t & 15;
  const int ng = t >> 4;

  if (blockIdx.x == 0) {
    for (int i = t; i < nb; i += 256) cursor[i] = 0;
  }

  float acc[8][8];
#pragma unroll
  for (int j = 0; j < 8; ++j)
#pragma unroll
    for (int i = 0; i < 8; ++i) acc[j][i] = 0.f;

  for (int half = 0; half < 2; ++half) {
    __syncthreads();
#pragma unroll
    for (int k = 0; k < 8; ++k) {
      int e4 = k * 256 + t;
      int oo = e4 >> 4;
      int f4 = (e4 & 15) * 4;
      float4 w = *(const float4*)&W[oo * 128 + half * 64 + f4];
      sWt[f4 + 0][oo] = w.x; sWt[f4 + 1][oo] = w.y;
      sWt[f4 + 2][oo] = w.z; sWt[f4 + 3][oo] = w.w;
    }
#pragma unroll
    for (int k = 0; k < 8; ++k) {
      int e4 = k * 256 + t;
      int nn = e4 >> 4;
      int f4 = (e4 & 15) * 4;
      int node = node0 + nn;
      float4 a = (node < n_nodes)
                     ? *(const float4*)&feat[(size_t)node * 128 + half * 64 + f4]
                     : make_float4(0.f, 0.f, 0.f, 0.f);
      *(float4*)&sA[nn][f4] = a;
    }
    __syncthreads();
#pragma unroll 4
    for (int f4 = 0; f4 < 64; f4 += 4) {
      float4 a[8];
#pragma unroll
      for (int j = 0; j < 8; ++j)
        a[j] = *(const float4*)&sA[ng + 16 * j][f4];
      float4 w1[4], w2[4];
#pragma unroll
      for (int k = 0; k < 4; ++k) {
        w1[k] = *(const float4*)&sWt[f4 + k][og * 4];
        w2[k] = *(const float4*)&sWt[f4 + k][og * 4 + 64];
      }
#pragma unroll
      for (int j = 0; j < 8; ++j) {
#pragma unroll
        for (int k = 0; k < 4; ++k) {
          float av = (&a[j].x)[k];
          acc[j][0] += av * w1[k].x; acc[j][1] += av * w1[k].y;
          acc[j][2] += av * w1[k].z; acc[j][3] += av * w1[k].w;
          acc[j][4] += av * w2[k].x; acc[j][5] += av * w2[k].y;
          acc[j][6] += av * w2[k].z; acc[j][7] += av * w2[k].w;
        }
      }
    }
  }
#pragma unroll
  for (int j = 0; j < 8; ++j) {
    int node = node0 + ng + 16 * j;
    if (node < n_nodes) {
      float nm = norm[node];
      uint2 ua, ub;
      ua.x = hpack(acc[j][0] * nm, acc[j][1] * nm);
      ua.y = hpack(acc[j][2] * nm, acc[j][3] * nm);
      ub.x = hpack(acc[j][4] * nm, acc[j][5] * nm);
      ub.y = hpack(acc[j][6] * nm, acc[j][7] * nm);
      ((uint2*)Yh)[(size_t)node * 32 + og] = ua;
      ((uint2*)Yh)[(size_t)node * 32 + og + 16] = ub;
    }
  }
}

// ---------------- partition: LDS counting-sort per chunk -> fixed-stride buckets ----------------
// record = src | (dst << 16)   (requires n_nodes <= 65536)
__global__ __launch_bounds__(256) void partition_kernel(
    const int* __restrict__ src, const int* __restrict__ dst,
    int* __restrict__ cursor, unsigned* __restrict__ recs, int n_edges, int nb) {
  __shared__ int lcount[512];
  __shared__ int lbase[512];
  __shared__ int gbase[512];
  __shared__ int aux[256];
  __shared__ unsigned stage[CHUNK];
  __shared__ int s_total;
  const int t = threadIdx.x;
  const int cbase = blockIdx.x * CHUNK;

  lcount[t] = 0; lcount[t + 256] = 0;
  __syncthreads();

  int es[16], ed[16], rk[16];
#pragma unroll
  for (int q = 0; q < 4; ++q) {
    int i4 = (cbase >> 2) + q * 256 + t;
    int e0 = i4 << 2;
    int4 sv, dv;
    if (e0 + 3 < n_edges) {
      sv = ((const int4*)src)[i4];
      dv = ((const int4*)dst)[i4];
    } else {
      sv.x = (e0 + 0 < n_edges) ? src[e0 + 0] : 0;
      sv.y = (e0 + 1 < n_edges) ? src[e0 + 1] : 0;
      sv.z = (e0 + 2 < n_edges) ? src[e0 + 2] : 0;
      sv.w = 0;
      dv.x = (e0 + 0 < n_edges) ? dst[e0 + 0] : -1;
      dv.y = (e0 + 1 < n_edges) ? dst[e0 + 1] : -1;
      dv.z = (e0 + 2 < n_edges) ? dst[e0 + 2] : -1;
      dv.w = -1;
    }
    es[q * 4 + 0] = sv.x; ed[q * 4 + 0] = dv.x;
    es[q * 4 + 1] = sv.y; ed[q * 4 + 1] = dv.y;
    es[q * 4 + 2] = sv.z; ed[q * 4 + 2] = dv.z;
    es[q * 4 + 3] = sv.w; ed[q * 4 + 3] = dv.w;
  }
#pragma unroll
  for (int k = 0; k < 16; ++k)
    rk[k] = (ed[k] >= 0) ? atomicAdd(&lcount[ed[k] >> NBITS], 1) : 0;
  __syncthreads();

  // block scan of lcount[512] -> lbase (exclusive)
  int a = lcount[2 * t] + lcount[2 * t + 1];
  aux[t] = a;
  __syncthreads();
  for (int off = 1; off < 256; off <<= 1) {
    int u = (t >= off) ? aux[t - off] : 0;
    __syncthreads();
    aux[t] += u;
    __syncthreads();
  }
  int ex = aux[t] - a;
  lbase[2 * t] = ex;
  lbase[2 * t + 1] = ex + lcount[2 * t];
  if (t == 255) s_total = aux[255];
  __syncthreads();

  // reserve ranges in fixed-stride buckets
  for (int b = t; b < nb; b += 256)
    gbase[b] = (lcount[b] > 0) ? ((b << BSHIFT) + atomicAdd(&cursor[b], lcount[b]))
                               : 0;
  __syncthreads();

  // scatter into LDS stage (bucket-sorted within chunk)
#pragma unroll
  for (int k = 0; k < 16; ++k) {
    if (ed[k] >= 0) {
      int b = ed[k] >> NBITS;
      stage[lbase[b] + rk[k]] = (unsigned)es[k] | ((unsigned)ed[k] << 16);
    }
  }
  __syncthreads();

  // dense copy out
  int total = s_total;
  for (int r = t; r < total; r += 256) {
    unsigned rec = stage[r];
    int b = (int)(rec >> (16 + NBITS));
    recs[gbase[b] + (r - lbase[b])] = rec;
  }
}

// ---------------- localize: per-bucket counting sort by node -> per-node CSR ----------------
__global__ __launch_bounds__(256) void localize_kernel(
    const unsigned* __restrict__ recs, const int* __restrict__ cursor,
    int* __restrict__ sorted_src, int* __restrict__ row_start,
    int* __restrict__ counts_d, int n_nodes) {
  __shared__ int lc[BNODES];
  __shared__ int ls[BNODES];
  __shared__ int cur[BNODES];
  const int t = threadIdx.x;
  const int b = blockIdx.x;
  const int cbeg = b << BSHIFT;
  const int cnt = cursor[b];

  if (t < BNODES) lc[t] = 0;
  __syncthreads();
  for (int i = t; i < cnt; i += 256) {
    unsigned rec = recs[cbeg + i];
    atomicAdd(&lc[(rec >> 16) & (BNODES - 1)], 1);
  }
  __syncthreads();
  if (t < BNODES) ls[t] = lc[t];
  __syncthreads();
  for (int off = 1; off < BNODES; off <<= 1) {
    int u = (t < BNODES && t >= off) ? ls[t - off] : 0;
    __syncthreads();
    if (t < BNODES) ls[t] += u;
    __syncthreads();
  }
  if (t < BNODES) {
    int ex = ls[t] - lc[t];
    cur[t] = ex;
    int node = (b << NBITS) + t;
    if (node < n_nodes) {
      counts_d[node] = lc[t];
      row_start[node] = cbeg + ex;
    }
  }
  __syncthreads();
  for (int i = t; i < cnt; i += 256) {
    unsigned rec = recs[cbeg + i];
    int nl = (rec >> 16) & (BNODES - 1);
    int p = atomicAdd(&cur[nl], 1);
    sorted_src[cbeg + p] = (int)(rec & 0xffffu);
  }
}

// ---------------- gather-reduce + fused tanh (fp16 Y rows) ----------------
// one 64-lane wave per node; coalesced id prefetch + readlane broadcast; unroll 8
__global__ __launch_bounds__(256) void gather_kernel(
    const unsigned* __restrict__ Yh, const int* __restrict__ sorted_src,
    const int* __restrict__ row_start, const int* __restrict__ counts_d,
    const float* __restrict__ norm, const float* __restrict__ b,
    float* __restrict__ out, int n_nodes) {
  int node = blockIdx.x * 4 + (threadIdx.x >> 6);
  if (node >= n_nodes) return;
  int lane = threadIdx.x & 63;
  int beg = row_start[node];
  int cnt = counts_d[node];
  float accx = 0.f, accy = 0.f;

  for (int base = 0; base < cnt; base += 64) {
    int m = cnt - base;
    if (m > 64) m = 64;
    int myid = (lane < m) ? sorted_src[beg + base + lane] : 0;  // coalesced
    int g = 0;
    for (; g + 8 <= m; g += 8) {
      int s0 = __builtin_amdgcn_readlane(myid, g + 0);
      int s1 = __builtin_amdgcn_readlane(myid, g + 1);
      int s2 = __builtin_amdgcn_readlane(myid, g + 2);
      int s3 = __builtin_amdgcn_readlane(myid, g + 3);
      int s4 = __builtin_amdgcn_readlane(myid, g + 4);
      int s5 = __builtin_amdgcn_readlane(myid, g + 5);
      int s6 = __builtin_amdgcn_readlane(myid, g + 6);
      int s7 = __builtin_amdgcn_readlane(myid, g + 7);
      unsigned u0 = Yh[(size_t)s0 * 64 + lane];
      unsigned u1 = Yh[(size_t)s1 * 64 + lane];
      unsigned u2 = Yh[(size_t)s2 * 64 + lane];
      unsigned u3 = Yh[(size_t)s3 * 64 + lane];
      unsigned u4 = Yh[(size_t)s4 * 64 + lane];
      unsigned u5 = Yh[(size_t)s5 * 64 + lane];
      unsigned u6 = Yh[(size_t)s6 * 64 + lane];
      unsigned u7 = Yh[(size_t)s7 * 64 + lane];
      float2 v0 = __half22float2(*reinterpret_cast<__half2*>(&u0));
      float2 v1 = __half22float2(*reinterpret_cast<__half2*>(&u1));
      float2 v2 = __half22float2(*reinterpret_cast<__half2*>(&u2));
      float2 v3 = __half22float2(*reinterpret_cast<__half2*>(&u3));
      float2 v4 = __half22float2(*reinterpret_cast<__half2*>(&u4));
      float2 v5 = __half22float2(*reinterpret_cast<__half2*>(&u5));
      float2 v6 = __half22float2(*reinterpret_cast<__half2*>(&u6));
      float2 v7 = __half22float2(*reinterpret_cast<__half2*>(&u7));
      accx += (v0.x + v1.x) + (v2.x + v3.x) + ((v4.x + v5.x) + (v6.x + v7.x));
      accy += (v0.y + v1.y) + (v2.y + v3.y) + ((v4.y + v5.y) + (v6.y + v7.y));
    }
    for (; g < m; ++g) {
      int s = __builtin_amdgcn_readlane(myid, g);
      unsigned u = Yh[(size_t)s * 64 + lane];
      float2 v = __half22float2(*reinterpret_cast<__half2*>(&u));
      accx += v.x;
      accy += v.y;
    }
  }
  float nm = norm[node];
  float2 bb = ((const float2*)b)[lane];
  float2 h;
  h.x = tanhf(accx * nm + bb.x);
  h.y = tanhf(accy * nm + bb.y);
  ((float2*)out)[(size_t)node * 64 + lane] = h;
}

extern "C" void kernel_launch(void* const* d_in, const int* in_sizes, int n_in,
                              void* d_out, int out_size, void* d_ws, size_t ws_size,
                              hipStream_t stream) {
  const float* feat = (const float*)d_in[0];   // [N,128]
  const float* norm = (const float*)d_in[1];   // [N,1]
  const float* W    = (const float*)d_in[2];   // [128,128]
  const float* b    = (const float*)d_in[3];   // [128]
  const int* src    = (const int*)d_in[4];     // [E]
  const int* dst    = (const int*)d_in[5];     // [E]
  float* out        = (float*)d_out;           // [N,128]

  const int n_nodes = in_sizes[1];
  const int n_edges = in_sizes[4];
  const int nb = (n_nodes + BNODES - 1) / BNODES;   // 391

  // workspace layout
  char* base = (char*)d_ws;
  unsigned* Yh = (unsigned*)base;                   // N*64 uints (fp16-packed rows)
  size_t off = (size_t)n_nodes * 64 * sizeof(unsigned);
  off = (off + 255) & ~(size_t)255;
  int* cursor = (int*)(base + off); off += (size_t)nb * 4;
  off = (off + 255) & ~(size_t)255;
  unsigned* recs = (unsigned*)(base + off); off += ((size_t)nb << BSHIFT) * 4;
  off = (off + 255) & ~(size_t)255;
  int* sorted_src = (int*)(base + off); off += ((size_t)nb << BSHIFT) * 4;
  off = (off + 255) & ~(size_t)255;
  int* row_start = (int*)(base + off); off += (size_t)n_nodes * 4;
  off = (off + 255) & ~(size_t)255;
  int* counts_d = (int*)(base + off); off += (size_t)n_nodes * 4;

  // 1) Yh = fp16( norm * (feat @ W^T) ); block 0 zeroes cursors
  int gblocks = (n_nodes + 127) / 128;
  gemm_kernel<<<gblocks, 256, 0, stream>>>(feat, norm, W, Yh, n_nodes, cursor, nb);

  // 2) partition edges into fixed-stride dst-buckets (dense writes)
  int chunks = (n_edges + CHUNK - 1) / CHUNK;
  partition_kernel<<<chunks, 256, 0, stream>>>(src, dst, cursor, recs, n_edges, nb);

  // 3) per-bucket counting sort -> per-node CSR
  localize_kernel<<<nb, 256, 0, stream>>>(recs, cursor, sorted_src,
                                          row_start, counts_d, n_nodes);

  // 4) wave-per-node gather-reduce + fused tanh(norm*agg + b)
  int nblocks = (n_nodes + 3) / 4;
  gather_kernel<<<nblocks, 256, 0, stream>>>(Yh, sorted_src, row_start, counts_d,
                                             norm, b, out, n_nodes);
}

// Round 13
// 75.337 us; speedup vs baseline: 10.0404x; 1.2098x over previous
//
#include <hip/hip_runtime.h>
#include <hip/hip_fp16.h>
#include <math.h>

#define NBITS 7            // log2(nodes per bucket)
#define BNODES 128         // nodes per bucket
#define CHUNK 4096         // edges per partition block
#define BSHIFT 12          // fixed bucket stride 4096 records

typedef _Float16 half4v __attribute__((ext_vector_type(4)));
typedef _Float16 half8v __attribute__((ext_vector_type(8)));
typedef float f32x4 __attribute__((ext_vector_type(4)));

__device__ __forceinline__ unsigned hpack(float a, float b) {
  __half2 h = __floats2half2_rn(a, b);
  return *reinterpret_cast<unsigned*>(&h);
}

// ---------------- MFMA GEMM: Yh[n] = fp16( norm[n] * (feat[n] @ W^T) ) ----------------
// 64 nodes/block, 256 thr = 4 waves; wave w computes rows w*16..+15 x all 128 outputs.
// f16 inputs (LDS), f32 accumulate, mfma_f32_16x16x32_f16.
union GemmSmem {
  struct {
    _Float16 Wh[128][136];   // [o][k], pad 8 f16 -> 272B row
    _Float16 Ah[64][136];    // [node][k]
  } s;
  float Cs[64][132];         // epilogue staging (aliases Wh region)
};

__global__ __launch_bounds__(256) void gemm_kernel(
    const float* __restrict__ feat, const float* __restrict__ norm,
    const float* __restrict__ W, unsigned* __restrict__ Yh, int n_nodes,
    int* __restrict__ cursor, int nb) {
  __shared__ __align__(16) GemmSmem sm;
  const int t = threadIdx.x;
  const int node0 = blockIdx.x * 64;

  if (blockIdx.x == 0) {
    for (int i = t; i < nb; i += 256) cursor[i] = 0;
  }

  // stage W -> f16 LDS [o][k]: 4096 float4, 16/thread
#pragma unroll
  for (int k = 0; k < 16; ++k) {
    int e4 = k * 256 + t;          // 0..4095
    int oo = e4 >> 5;              // 0..127
    int f4 = (e4 & 31) * 4;        // 0..124
    float4 w = *(const float4*)&W[oo * 128 + f4];
    half4v h;
    h.x = (_Float16)w.x; h.y = (_Float16)w.y;
    h.z = (_Float16)w.z; h.w = (_Float16)w.w;
    *(half4v*)&sm.s.Wh[oo][f4] = h;
  }
  // stage feat tile -> f16 LDS [node][k]: 2048 float4, 8/thread
#pragma unroll
  for (int k = 0; k < 8; ++k) {
    int e4 = k * 256 + t;          // 0..2047
    int nn = e4 >> 5;              // 0..63
    int f4 = (e4 & 31) * 4;
    int node = node0 + nn;
    float4 a = (node < n_nodes)
                   ? *(const float4*)&feat[(size_t)node * 128 + f4]
                   : make_float4(0.f, 0.f, 0.f, 0.f);
    half4v h;
    h.x = (_Float16)a.x; h.y = (_Float16)a.y;
    h.z = (_Float16)a.z; h.w = (_Float16)a.w;
    *(half4v*)&sm.s.Ah[nn][f4] = h;
  }
  __syncthreads();

  const int wv = t >> 6;           // wave 0..3 -> rows wv*16..+15
  const int l = t & 63;
  const int row16 = l & 15;        // A row / D col within 16-tile
  const int kq = l >> 4;           // 0..3: k-chunk (A/B), row-quad (D)

  f32x4 acc[8];
#pragma unroll
  for (int nt = 0; nt < 8; ++nt) acc[nt] = (f32x4){0.f, 0.f, 0.f, 0.f};

#pragma unroll
  for (int ks = 0; ks < 4; ++ks) {
    half8v afrag = *(const half8v*)&sm.s.Ah[wv * 16 + row16][kq * 8 + ks * 32];
#pragma unroll
    for (int nt = 0; nt < 8; ++nt) {
      half8v bfrag = *(const half8v*)&sm.s.Wh[nt * 16 + row16][kq * 8 + ks * 32];
      acc[nt] = __builtin_amdgcn_mfma_f32_16x16x32_f16(afrag, bfrag, acc[nt], 0, 0, 0);
    }
  }
  __syncthreads();   // done reading Wh/Ah; Cs aliases Wh

  // D: col = l&15 (=row16), row = kq*4 + r  -> Cs[node_local][out]
#pragma unroll
  for (int nt = 0; nt < 8; ++nt)
#pragma unroll
    for (int r = 0; r < 4; ++r)
      sm.Cs[wv * 16 + kq * 4 + r][nt * 16 + row16] = acc[nt][r];
  __syncthreads();

  // pack: 64 nodes x 128 f32 -> fp16 pairs; 2048 uint2, 8/thread
#pragma unroll
  for (int k = 0; k < 8; ++k) {
    int p = k * 256 + t;           // 0..2047
    int nn = p >> 5;               // 0..63
    int q = p & 31;                // 4 cols: 4q..4q+3
    int node = node0 + nn;
    if (node < n_nodes) {
      float nm = norm[node];
      float4 v = *(float4*)&sm.Cs[nn][q * 4];
      uint2 u;
      u.x = hpack(v.x * nm, v.y * nm);
      u.y = hpack(v.z * nm, v.w * nm);
      ((uint2*)Yh)[(size_t)node * 32 + q] = u;
    }
  }
}

// ---------------- partition: LDS counting-sort per chunk -> fixed-stride buckets ----------------
// record = src | (dst << 16)   (requires n_nodes <= 65536)
__global__ __launch_bounds__(256) void partition_kernel(
    const int* __restrict__ src, const int* __restrict__ dst,
    int* __restrict__ cursor, unsigned* __restrict__ recs, int n_edges, int nb) {
  __shared__ int lcount[512];
  __shared__ int lbase[512];
  __shared__ int gbase[512];
  __shared__ int aux[256];
  __shared__ unsigned stage[CHUNK];
  __shared__ int s_total;
  const int t = threadIdx.x;
  const int cbase = blockIdx.x * CHUNK;

  lcount[t] = 0; lcount[t + 256] = 0;
  __syncthreads();

  int es[16], ed[16], rk[16];
#pragma unroll
  for (int q = 0; q < 4; ++q) {
    int i4 = (cbase >> 2) + q * 256 + t;
    int e0 = i4 << 2;
    int4 sv, dv;
    if (e0 + 3 < n_edges) {
      sv = ((const int4*)src)[i4];
      dv = ((const int4*)dst)[i4];
    } else {
      sv.x = (e0 + 0 < n_edges) ? src[e0 + 0] : 0;
      sv.y = (e0 + 1 < n_edges) ? src[e0 + 1] : 0;
      sv.z = (e0 + 2 < n_edges) ? src[e0 + 2] : 0;
      sv.w = 0;
      dv.x = (e0 + 0 < n_edges) ? dst[e0 + 0] : -1;
      dv.y = (e0 + 1 < n_edges) ? dst[e0 + 1] : -1;
      dv.z = (e0 + 2 < n_edges) ? dst[e0 + 2] : -1;
      dv.w = -1;
    }
    es[q * 4 + 0] = sv.x; ed[q * 4 + 0] = dv.x;
    es[q * 4 + 1] = sv.y; ed[q * 4 + 1] = dv.y;
    es[q * 4 + 2] = sv.z; ed[q * 4 + 2] = dv.z;
    es[q * 4 + 3] = sv.w; ed[q * 4 + 3] = dv.w;
  }
#pragma unroll
  for (int k = 0; k < 16; ++k)
    rk[k] = (ed[k] >= 0) ? atomicAdd(&lcount[ed[k] >> NBITS], 1) : 0;
  __syncthreads();

  int a = lcount[2 * t] + lcount[2 * t + 1];
  aux[t] = a;
  __syncthreads();
  for (int off = 1; off < 256; off <<= 1) {
    int u = (t >= off) ? aux[t - off] : 0;
    __syncthreads();
    aux[t] += u;
    __syncthreads();
  }
  int ex = aux[t] - a;
  lbase[2 * t] = ex;
  lbase[2 * t + 1] = ex + lcount[2 * t];
  if (t == 255) s_total = aux[255];
  __syncthreads();

  for (int b = t; b < nb; b += 256)
    gbase[b] = (lcount[b] > 0) ? ((b << BSHIFT) + atomicAdd(&cursor[b], lcount[b]))
                               : 0;
  __syncthreads();

#pragma unroll
  for (int k = 0; k < 16; ++k) {
    if (ed[k] >= 0) {
      int b = ed[k] >> NBITS;
      stage[lbase[b] + rk[k]] = (unsigned)es[k] | ((unsigned)ed[k] << 16);
    }
  }
  __syncthreads();

  int total = s_total;
  for (int r = t; r < total; r += 256) {
    unsigned rec = stage[r];
    int b = (int)(rec >> (16 + NBITS));
    recs[gbase[b] + (r - lbase[b])] = rec;
  }
}

// ---------------- localize: per-bucket counting sort by node -> per-node CSR ----------------
__global__ __launch_bounds__(256) void localize_kernel(
    const unsigned* __restrict__ recs, const int* __restrict__ cursor,
    int* __restrict__ sorted_src, int* __restrict__ row_start,
    int* __restrict__ counts_d, int n_nodes) {
  __shared__ int lc[BNODES];
  __shared__ int ls[BNODES];
  __shared__ int cur[BNODES];
  const int t = threadIdx.x;
  const int b = blockIdx.x;
  const int cbeg = b << BSHIFT;
  const int cnt = cursor[b];

  if (t < BNODES) lc[t] = 0;
  __syncthreads();
  for (int i = t; i < cnt; i += 256) {
    unsigned rec = recs[cbeg + i];
    atomicAdd(&lc[(rec >> 16) & (BNODES - 1)], 1);
  }
  __syncthreads();
  if (t < BNODES) ls[t] = lc[t];
  __syncthreads();
  for (int off = 1; off < BNODES; off <<= 1) {
    int u = (t < BNODES && t >= off) ? ls[t - off] : 0;
    __syncthreads();
    if (t < BNODES) ls[t] += u;
    __syncthreads();
  }
  if (t < BNODES) {
    int ex = ls[t] - lc[t];
    cur[t] = ex;
    int node = (b << NBITS) + t;
    if (node < n_nodes) {
      counts_d[node] = lc[t];
      row_start[node] = cbeg + ex;
    }
  }
  __syncthreads();
  for (int i = t; i < cnt; i += 256) {
    unsigned rec = recs[cbeg + i];
    int nl = (rec >> 16) & (BNODES - 1);
    int p = atomicAdd(&cur[nl], 1);
    sorted_src[cbeg + p] = (int)(rec & 0xffffu);
  }
}

// ---------------- gather-reduce + fused tanh (fp16 Y rows) ----------------
__global__ __launch_bounds__(256) void gather_kernel(
    const unsigned* __restrict__ Yh, const int* __restrict__ sorted_src,
    const int* __restrict__ row_start, const int* __restrict__ counts_d,
    const float* __restrict__ norm, const float* __restrict__ b,
    float* __restrict__ out, int n_nodes) {
  int node = blockIdx.x * 4 + (threadIdx.x >> 6);
  if (node >= n_nodes) return;
  int lane = threadIdx.x & 63;
  int beg = row_start[node];
  int cnt = counts_d[node];
  float accx = 0.f, accy = 0.f;

  for (int base = 0; base < cnt; base += 64) {
    int m = cnt - base;
    if (m > 64) m = 64;
    int myid = (lane < m) ? sorted_src[beg + base + lane] : 0;  // coalesced
    int g = 0;
    for (; g + 8 <= m; g += 8) {
      int s0 = __builtin_amdgcn_readlane(myid, g + 0);
      int s1 = __builtin_amdgcn_readlane(myid, g + 1);
      int s2 = __builtin_amdgcn_readlane(myid, g + 2);
      int s3 = __builtin_amdgcn_readlane(myid, g + 3);
      int s4 = __builtin_amdgcn_readlane(myid, g + 4);
      int s5 = __builtin_amdgcn_readlane(myid, g + 5);
      int s6 = __builtin_amdgcn_readlane(myid, g + 6);
      int s7 = __builtin_amdgcn_readlane(myid, g + 7);
      unsigned u0 = Yh[(size_t)s0 * 64 + lane];
      unsigned u1 = Yh[(size_t)s1 * 64 + lane];
      unsigned u2 = Yh[(size_t)s2 * 64 + lane];
      unsigned u3 = Yh[(size_t)s3 * 64 + lane];
      unsigned u4 = Yh[(size_t)s4 * 64 + lane];
      unsigned u5 = Yh[(size_t)s5 * 64 + lane];
      unsigned u6 = Yh[(size_t)s6 * 64 + lane];
      unsigned u7 = Yh[(size_t)s7 * 64 + lane];
      float2 v0 = __half22float2(*reinterpret_cast<__half2*>(&u0));
      float2 v1 = __half22float2(*reinterpret_cast<__half2*>(&u1));
      float2 v2 = __half22float2(*reinterpret_cast<__half2*>(&u2));
      float2 v3 = __half22float2(*reinterpret_cast<__half2*>(&u3));
      float2 v4 = __half22float2(*reinterpret_cast<__half2*>(&u4));
      float2 v5 = __half22float2(*reinterpret_cast<__half2*>(&u5));
      float2 v6 = __half22float2(*reinterpret_cast<__half2*>(&u6));
      float2 v7 = __half22float2(*reinterpret_cast<__half2*>(&u7));
      accx += (v0.x + v1.x) + (v2.x + v3.x) + ((v4.x + v5.x) + (v6.x + v7.x));
      accy += (v0.y + v1.y) + (v2.y + v3.y) + ((v4.y + v5.y) + (v6.y + v7.y));
    }
    for (; g < m; ++g) {
      int s = __builtin_amdgcn_readlane(myid, g);
      unsigned u = Yh[(size_t)s * 64 + lane];
      float2 v = __half22float2(*reinterpret_cast<__half2*>(&u));
      accx += v.x;
      accy += v.y;
    }
  }
  float nm = norm[node];
  float2 bb = ((const float2*)b)[lane];
  float2 h;
  h.x = tanhf(accx * nm + bb.x);
  h.y = tanhf(accy * nm + bb.y);
  ((float2*)out)[(size_t)node * 64 + lane] = h;
}

extern "C" void kernel_launch(void* const* d_in, const int* in_sizes, int n_in,
                              void* d_out, int out_size, void* d_ws, size_t ws_size,
                              hipStream_t stream) {
  const float* feat = (const float*)d_in[0];   // [N,128]
  const float* norm = (const float*)d_in[1];   // [N,1]
  const float* W    = (const float*)d_in[2];   // [128,128]
  const float* b    = (const float*)d_in[3];   // [128]
  const int* src    = (const int*)d_in[4];     // [E]
  const int* dst    = (const int*)d_in[5];     // [E]
  float* out        = (float*)d_out;           // [N,128]

  const int n_nodes = in_sizes[1];
  const int n_edges = in_sizes[4];
  const int nb = (n_nodes + BNODES - 1) / BNODES;   // 391

  // workspace layout
  char* base = (char*)d_ws;
  unsigned* Yh = (unsigned*)base;                   // N*64 uints (fp16-packed rows)
  size_t off = (size_t)n_nodes * 64 * sizeof(unsigned);
  off = (off + 255) & ~(size_t)255;
  int* cursor = (int*)(base + off); off += (size_t)nb * 4;
  off = (off + 255) & ~(size_t)255;
  unsigned* recs = (unsigned*)(base + off); off += ((size_t)nb << BSHIFT) * 4;
  off = (off + 255) & ~(size_t)255;
  int* sorted_src = (int*)(base + off); off += ((size_t)nb << BSHIFT) * 4;
  off = (off + 255) & ~(size_t)255;
  int* row_start = (int*)(base + off); off += (size_t)n_nodes * 4;
  off = (off + 255) & ~(size_t)255;
  int* counts_d = (int*)(base + off); off += (size_t)n_nodes * 4;

  // 1) Yh = fp16( norm * (feat @ W^T) ) via MFMA; block 0 zeroes cursors
  int gblocks = (n_nodes + 63) / 64;
  gemm_kernel<<<gblocks, 256, 0, stream>>>(feat, norm, W, Yh, n_nodes, cursor, nb);

  // 2) partition edges into fixed-stride dst-buckets (dense writes)
  int chunks = (n_edges + CHUNK - 1) / CHUNK;
  partition_kernel<<<chunks, 256, 0, stream>>>(src, dst, cursor, recs, n_edges, nb);

  // 3) per-bucket counting sort -> per-node CSR
  localize_kernel<<<nb, 256, 0, stream>>>(recs, cursor, sorted_src,
                                          row_start, counts_d, n_nodes);

  // 4) wave-per-node gather-reduce + fused tanh(norm*agg + b)
  int nblocks = (n_nodes + 3) / 4;
  gather_kernel<<<nblocks, 256, 0, stream>>>(Yh, sorted_src, row_start, counts_d,
                                             norm, b, out, n_nodes);
}

// Round 14
// 74.466 us; speedup vs baseline: 10.1579x; 1.0117x over previous
//
#include <hip/hip_runtime.h>
#include <hip/hip_fp16.h>
#include <math.h>

#define NBITS 7            // log2(nodes per bucket)
#define BNODES 128         // nodes per bucket
#define CHUNK 4096         // edges per partition block
#define BSHIFT 12          // fixed bucket stride 4096 records

typedef _Float16 half4v __attribute__((ext_vector_type(4)));
typedef _Float16 half8v __attribute__((ext_vector_type(8)));
typedef float f32x4 __attribute__((ext_vector_type(4)));

__device__ __forceinline__ unsigned hpack(float a, float b) {
  __half2 h = __floats2half2_rn(a, b);
  return *reinterpret_cast<unsigned*>(&h);
}

// ---------------- MFMA GEMM: Yh[n] = fp16( norm[n] * (feat[n] @ W^T) ) ----------------
// 64 nodes/block, 4 waves; wave wv owns nodes wv*16..+15 x all 128 outputs.
// Operand order mfma(W-tile, feat-tile): D col = node (lane&15), rows = outputs
// -> each lane stores its node's outputs directly as uint2 (no LDS epilogue).
__global__ __launch_bounds__(256) void gemm_kernel(
    const float* __restrict__ feat, const float* __restrict__ norm,
    const float* __restrict__ W, unsigned* __restrict__ Yh, int n_nodes,
    int* __restrict__ cursor, int nb) {
  __shared__ __align__(16) _Float16 Wh[128][136];   // [o][k]
  __shared__ __align__(16) _Float16 Ah[64][136];    // [node][k]
  const int t = threadIdx.x;
  const int node0 = blockIdx.x * 64;

  if (blockIdx.x == 0) {
    for (int i = t; i < nb; i += 256) cursor[i] = 0;
  }

  // stage W -> f16 LDS [o][k]: 4096 float4, 16/thread
#pragma unroll
  for (int k = 0; k < 16; ++k) {
    int e4 = k * 256 + t;          // 0..4095
    int oo = e4 >> 5;              // 0..127
    int f4 = (e4 & 31) * 4;        // 0..124
    float4 w = *(const float4*)&W[oo * 128 + f4];
    half4v h;
    h.x = (_Float16)w.x; h.y = (_Float16)w.y;
    h.z = (_Float16)w.z; h.w = (_Float16)w.w;
    *(half4v*)&Wh[oo][f4] = h;
  }
  // stage feat tile -> f16 LDS [node][k]: 2048 float4, 8/thread
#pragma unroll
  for (int k = 0; k < 8; ++k) {
    int e4 = k * 256 + t;          // 0..2047
    int nn = e4 >> 5;              // 0..63
    int f4 = (e4 & 31) * 4;
    int node = node0 + nn;
    float4 a = (node < n_nodes)
                   ? *(const float4*)&feat[(size_t)node * 128 + f4]
                   : make_float4(0.f, 0.f, 0.f, 0.f);
    half4v h;
    h.x = (_Float16)a.x; h.y = (_Float16)a.y;
    h.z = (_Float16)a.z; h.w = (_Float16)a.w;
    *(half4v*)&Ah[nn][f4] = h;
  }
  __syncthreads();

  const int wv = t >> 6;           // wave 0..3 -> nodes wv*16..+15
  const int l = t & 63;
  const int row16 = l & 15;
  const int kq = l >> 4;           // 0..3

  f32x4 acc[8];
#pragma unroll
  for (int ot = 0; ot < 8; ++ot) acc[ot] = (f32x4){0.f, 0.f, 0.f, 0.f};

#pragma unroll
  for (int ks = 0; ks < 4; ++ks) {
    half8v nfrag = *(const half8v*)&Ah[wv * 16 + row16][kq * 8 + ks * 32];
#pragma unroll
    for (int ot = 0; ot < 8; ++ot) {
      half8v wfrag = *(const half8v*)&Wh[ot * 16 + row16][kq * 8 + ks * 32];
      acc[ot] = __builtin_amdgcn_mfma_f32_16x16x32_f16(wfrag, nfrag, acc[ot], 0, 0, 0);
    }
  }

  // D: col = row16 -> node, row = kq*4+r -> output ot*16+kq*4+r
  int node = node0 + wv * 16 + row16;
  if (node < n_nodes) {
    float nm = norm[node];
#pragma unroll
    for (int ot = 0; ot < 8; ++ot) {
      uint2 u;
      u.x = hpack(acc[ot][0] * nm, acc[ot][1] * nm);
      u.y = hpack(acc[ot][2] * nm, acc[ot][3] * nm);
      ((uint2*)Yh)[(size_t)node * 32 + ot * 4 + kq] = u;
    }
  }
}

// ---------------- partition: LDS counting-sort per chunk -> fixed-stride buckets ----------------
// record = src | (dst << 16)   (requires n_nodes <= 65536)
__global__ __launch_bounds__(256) void partition_kernel(
    const int* __restrict__ src, const int* __restrict__ dst,
    int* __restrict__ cursor, unsigned* __restrict__ recs, int n_edges, int nb) {
  __shared__ int lcount[512];
  __shared__ int lbase[512];
  __shared__ int gbase[512];
  __shared__ int aux[256];
  __shared__ unsigned stage[CHUNK];
  __shared__ int s_total;
  const int t = threadIdx.x;
  const int cbase = blockIdx.x * CHUNK;

  lcount[t] = 0; lcount[t + 256] = 0;
  __syncthreads();

  int es[16], ed[16], rk[16];
#pragma unroll
  for (int q = 0; q < 4; ++q) {
    int i4 = (cbase >> 2) + q * 256 + t;
    int e0 = i4 << 2;
    int4 sv, dv;
    if (e0 + 3 < n_edges) {
      sv = ((const int4*)src)[i4];
      dv = ((const int4*)dst)[i4];
    } else {
      sv.x = (e0 + 0 < n_edges) ? src[e0 + 0] : 0;
      sv.y = (e0 + 1 < n_edges) ? src[e0 + 1] : 0;
      sv.z = (e0 + 2 < n_edges) ? src[e0 + 2] : 0;
      sv.w = 0;
      dv.x = (e0 + 0 < n_edges) ? dst[e0 + 0] : -1;
      dv.y = (e0 + 1 < n_edges) ? dst[e0 + 1] : -1;
      dv.z = (e0 + 2 < n_edges) ? dst[e0 + 2] : -1;
      dv.w = -1;
    }
    es[q * 4 + 0] = sv.x; ed[q * 4 + 0] = dv.x;
    es[q * 4 + 1] = sv.y; ed[q * 4 + 1] = dv.y;
    es[q * 4 + 2] = sv.z; ed[q * 4 + 2] = dv.z;
    es[q * 4 + 3] = sv.w; ed[q * 4 + 3] = dv.w;
  }
#pragma unroll
  for (int k = 0; k < 16; ++k)
    rk[k] = (ed[k] >= 0) ? atomicAdd(&lcount[ed[k] >> NBITS], 1) : 0;
  __syncthreads();

  int a = lcount[2 * t] + lcount[2 * t + 1];
  aux[t] = a;
  __syncthreads();
  for (int off = 1; off < 256; off <<= 1) {
    int u = (t >= off) ? aux[t - off] : 0;
    __syncthreads();
    aux[t] += u;
    __syncthreads();
  }
  int ex = aux[t] - a;
  lbase[2 * t] = ex;
  lbase[2 * t + 1] = ex + lcount[2 * t];
  if (t == 255) s_total = aux[255];
  __syncthreads();

  for (int b = t; b < nb; b += 256)
    gbase[b] = (lcount[b] > 0) ? ((b << BSHIFT) + atomicAdd(&cursor[b], lcount[b]))
                               : 0;
  __syncthreads();

#pragma unroll
  for (int k = 0; k < 16; ++k) {
    if (ed[k] >= 0) {
      int b = ed[k] >> NBITS;
      stage[lbase[b] + rk[k]] = (unsigned)es[k] | ((unsigned)ed[k] << 16);
    }
  }
  __syncthreads();

  int total = s_total;
  for (int r = t; r < total; r += 256) {
    unsigned rec = stage[r];
    int b = (int)(rec >> (16 + NBITS));
    recs[gbase[b] + (r - lbase[b])] = rec;
  }
}

// ---------------- localize: per-bucket counting sort by node -> per-node CSR ----------------
__global__ __launch_bounds__(512) void localize_kernel(
    const unsigned* __restrict__ recs, const int* __restrict__ cursor,
    int* __restrict__ sorted_src, int* __restrict__ row_start,
    int* __restrict__ counts_d, int n_nodes) {
  __shared__ int lc[BNODES];
  __shared__ int ls[BNODES];
  __shared__ int cur[BNODES];
  const int t = threadIdx.x;
  const int b = blockIdx.x;
  const int cbeg = b << BSHIFT;
  const int cnt = cursor[b];

  if (t < BNODES) lc[t] = 0;
  __syncthreads();
  for (int i = t; i < cnt; i += 512) {
    unsigned rec = recs[cbeg + i];
    atomicAdd(&lc[(rec >> 16) & (BNODES - 1)], 1);
  }
  __syncthreads();
  if (t < BNODES) ls[t] = lc[t];
  __syncthreads();
  for (int off = 1; off < BNODES; off <<= 1) {
    int u = (t < BNODES && t >= off) ? ls[t - off] : 0;
    __syncthreads();
    if (t < BNODES) ls[t] += u;
    __syncthreads();
  }
  if (t < BNODES) {
    int ex = ls[t] - lc[t];
    cur[t] = ex;
    int node = (b << NBITS) + t;
    if (node < n_nodes) {
      counts_d[node] = lc[t];
      row_start[node] = cbeg + ex;
    }
  }
  __syncthreads();
  for (int i = t; i < cnt; i += 512) {
    unsigned rec = recs[cbeg + i];
    int nl = (rec >> 16) & (BNODES - 1);
    int p = atomicAdd(&cur[nl], 1);
    sorted_src[cbeg + p] = (int)(rec & 0xffffu);
  }
}

// ---------------- gather-reduce + fused tanh (fp16 Y rows) ----------------
// one 64-lane wave per node; coalesced id prefetch + readlane; 16 loads in flight
__global__ __launch_bounds__(256) void gather_kernel(
    const unsigned* __restrict__ Yh, const int* __restrict__ sorted_src,
    const int* __restrict__ row_start, const int* __restrict__ counts_d,
    const float* __restrict__ norm, const float* __restrict__ b,
    float* __restrict__ out, int n_nodes) {
  int node = blockIdx.x * 4 + (threadIdx.x >> 6);
  if (node >= n_nodes) return;
  int lane = threadIdx.x & 63;
  int beg = row_start[node];
  int cnt = counts_d[node];
  float accx = 0.f, accy = 0.f;

  for (int base = 0; base < cnt; base += 64) {
    int m = cnt - base;
    if (m > 64) m = 64;
    int myid = (lane < m) ? sorted_src[beg + base + lane] : 0;  // coalesced
    int g = 0;
    for (; g + 16 <= m; g += 16) {
      int sid[16];
      unsigned uu[16];
#pragma unroll
      for (int q = 0; q < 16; ++q) sid[q] = __builtin_amdgcn_readlane(myid, g + q);
#pragma unroll
      for (int q = 0; q < 16; ++q) uu[q] = Yh[(size_t)sid[q] * 64 + lane];
#pragma unroll
      for (int q = 0; q < 16; ++q) {
        float2 v = __half22float2(*reinterpret_cast<__half2*>(&uu[q]));
        accx += v.x;
        accy += v.y;
      }
    }
    for (; g + 8 <= m; g += 8) {
      int sid[8];
      unsigned uu[8];
#pragma unroll
      for (int q = 0; q < 8; ++q) sid[q] = __builtin_amdgcn_readlane(myid, g + q);
#pragma unroll
      for (int q = 0; q < 8; ++q) uu[q] = Yh[(size_t)sid[q] * 64 + lane];
#pragma unroll
      for (int q = 0; q < 8; ++q) {
        float2 v = __half22float2(*reinterpret_cast<__half2*>(&uu[q]));
        accx += v.x;
        accy += v.y;
      }
    }
    for (; g < m; ++g) {
      int s = __builtin_amdgcn_readlane(myid, g);
      unsigned u = Yh[(size_t)s * 64 + lane];
      float2 v = __half22float2(*reinterpret_cast<__half2*>(&u));
      accx += v.x;
      accy += v.y;
    }
  }
  float nm = norm[node];
  float2 bb = ((const float2*)b)[lane];
  float2 h;
  h.x = tanhf(accx * nm + bb.x);
  h.y = tanhf(accy * nm + bb.y);
  ((float2*)out)[(size_t)node * 64 + lane] = h;
}

extern "C" void kernel_launch(void* const* d_in, const int* in_sizes, int n_in,
                              void* d_out, int out_size, void* d_ws, size_t ws_size,
                              hipStream_t stream) {
  const float* feat = (const float*)d_in[0];   // [N,128]
  const float* norm = (const float*)d_in[1];   // [N,1]
  const float* W    = (const float*)d_in[2];   // [128,128]
  const float* b    = (const float*)d_in[3];   // [128]
  const int* src    = (const int*)d_in[4];     // [E]
  const int* dst    = (const int*)d_in[5];     // [E]
  float* out        = (float*)d_out;           // [N,128]

  const int n_nodes = in_sizes[1];
  const int n_edges = in_sizes[4];
  const int nb = (n_nodes + BNODES - 1) / BNODES;   // 391

  // workspace layout
  char* base = (char*)d_ws;
  unsigned* Yh = (unsigned*)base;                   // N*64 uints (fp16-packed rows)
  size_t off = (size_t)n_nodes * 64 * sizeof(unsigned);
  off = (off + 255) & ~(size_t)255;
  int* cursor = (int*)(base + off); off += (size_t)nb * 4;
  off = (off + 255) & ~(size_t)255;
  unsigned* recs = (unsigned*)(base + off); off += ((size_t)nb << BSHIFT) * 4;
  off = (off + 255) & ~(size_t)255;
  int* sorted_src = (int*)(base + off); off += ((size_t)nb << BSHIFT) * 4;
  off = (off + 255) & ~(size_t)255;
  int* row_start = (int*)(base + off); off += (size_t)n_nodes * 4;
  off = (off + 255) & ~(size_t)255;
  int* counts_d = (int*)(base + off); off += (size_t)n_nodes * 4;

  // 1) Yh = fp16( norm * (feat @ W^T) ) via MFMA; block 0 zeroes cursors
  int gblocks = (n_nodes + 63) / 64;
  gemm_kernel<<<gblocks, 256, 0, stream>>>(feat, norm, W, Yh, n_nodes, cursor, nb);

  // 2) partition edges into fixed-stride dst-buckets (dense writes)
  int chunks = (n_edges + CHUNK - 1) / CHUNK;
  partition_kernel<<<chunks, 256, 0, stream>>>(src, dst, cursor, recs, n_edges, nb);

  // 3) per-bucket counting sort -> per-node CSR
  localize_kernel<<<nb, 512, 0, stream>>>(recs, cursor, sorted_src,
                                          row_start, counts_d, n_nodes);

  // 4) wave-per-node gather-reduce + fused tanh(norm*agg + b)
  int nblocks = (n_nodes + 3) / 4;
  gather_kernel<<<nblocks, 256, 0, stream>>>(Yh, sorted_src, row_start, counts_d,
                                             norm, b, out, n_nodes);
}

// Round 15
// 73.153 us; speedup vs baseline: 10.3401x; 1.0179x over previous
//
#include <hip/hip_runtime.h>
#include <hip/hip_fp16.h>
#include <math.h>

#define NBITS 7            // log2(nodes per bucket)
#define BNODES 128         // nodes per bucket
#define CHUNK 4096         // edges per partition block
#define BSHIFT 12          // fixed bucket stride 4096 records

typedef _Float16 half4v __attribute__((ext_vector_type(4)));
typedef _Float16 half8v __attribute__((ext_vector_type(8)));
typedef float f32x4 __attribute__((ext_vector_type(4)));

__device__ __forceinline__ unsigned hpack(float a, float b) {
  __half2 h = __floats2half2_rn(a, b);
  return *reinterpret_cast<unsigned*>(&h);
}

// ---------------- fused: blocks [0,gblocks) = MFMA GEMM; [gblocks,..) = partition ----------------
union FusedSmem {
  struct {
    _Float16 Wh[128][136];   // [o][k]
    _Float16 Ah[64][136];    // [node][k]
  } g;
  struct {
    int lcount[512];
    int lbase[512];
    int gbase[512];
    int aux[256];
    unsigned stage[CHUNK];
    int s_total;
  } p;
};

__global__ __launch_bounds__(256) void fused_kernel(
    const float* __restrict__ feat, const float* __restrict__ norm,
    const float* __restrict__ W, unsigned* __restrict__ Yh, int n_nodes,
    const int* __restrict__ src, const int* __restrict__ dst,
    int* __restrict__ cursor, unsigned* __restrict__ recs, int n_edges,
    int nb, int gblocks) {
  __shared__ __align__(16) FusedSmem sm;
  const int t = threadIdx.x;

  if ((int)blockIdx.x < gblocks) {
    // ================= GEMM path =================
    const int node0 = blockIdx.x * 64;

    // stage W -> f16 LDS [o][k]: 4096 float4, 16/thread
#pragma unroll
    for (int k = 0; k < 16; ++k) {
      int e4 = k * 256 + t;
      int oo = e4 >> 5;
      int f4 = (e4 & 31) * 4;
      float4 w = *(const float4*)&W[oo * 128 + f4];
      half4v h;
      h.x = (_Float16)w.x; h.y = (_Float16)w.y;
      h.z = (_Float16)w.z; h.w = (_Float16)w.w;
      *(half4v*)&sm.g.Wh[oo][f4] = h;
    }
    // stage feat tile -> f16 LDS [node][k]: 2048 float4, 8/thread
#pragma unroll
    for (int k = 0; k < 8; ++k) {
      int e4 = k * 256 + t;
      int nn = e4 >> 5;
      int f4 = (e4 & 31) * 4;
      int node = node0 + nn;
      float4 a = (node < n_nodes)
                     ? *(const float4*)&feat[(size_t)node * 128 + f4]
                     : make_float4(0.f, 0.f, 0.f, 0.f);
      half4v h;
      h.x = (_Float16)a.x; h.y = (_Float16)a.y;
      h.z = (_Float16)a.z; h.w = (_Float16)a.w;
      *(half4v*)&sm.g.Ah[nn][f4] = h;
    }
    __syncthreads();

    const int wv = t >> 6;
    const int l = t & 63;
    const int row16 = l & 15;
    const int kq = l >> 4;

    f32x4 acc[8];
#pragma unroll
    for (int ot = 0; ot < 8; ++ot) acc[ot] = (f32x4){0.f, 0.f, 0.f, 0.f};

#pragma unroll
    for (int ks = 0; ks < 4; ++ks) {
      half8v nfrag = *(const half8v*)&sm.g.Ah[wv * 16 + row16][kq * 8 + ks * 32];
#pragma unroll
      for (int ot = 0; ot < 8; ++ot) {
        half8v wfrag = *(const half8v*)&sm.g.Wh[ot * 16 + row16][kq * 8 + ks * 32];
        acc[ot] = __builtin_amdgcn_mfma_f32_16x16x32_f16(wfrag, nfrag, acc[ot], 0, 0, 0);
      }
    }

    int node = node0 + wv * 16 + row16;
    if (node < n_nodes) {
      float nm = norm[node];
#pragma unroll
      for (int ot = 0; ot < 8; ++ot) {
        uint2 u;
        u.x = hpack(acc[ot][0] * nm, acc[ot][1] * nm);
        u.y = hpack(acc[ot][2] * nm, acc[ot][3] * nm);
        ((uint2*)Yh)[(size_t)node * 32 + ot * 4 + kq] = u;
      }
    }
  } else {
    // ================= partition path =================
    const int cbase = ((int)blockIdx.x - gblocks) * CHUNK;

    sm.p.lcount[t] = 0; sm.p.lcount[t + 256] = 0;
    __syncthreads();

    int es[16], ed[16], rk[16];
#pragma unroll
    for (int q = 0; q < 4; ++q) {
      int i4 = (cbase >> 2) + q * 256 + t;
      int e0 = i4 << 2;
      int4 sv, dv;
      if (e0 + 3 < n_edges) {
        sv = ((const int4*)src)[i4];
        dv = ((const int4*)dst)[i4];
      } else {
        sv.x = (e0 + 0 < n_edges) ? src[e0 + 0] : 0;
        sv.y = (e0 + 1 < n_edges) ? src[e0 + 1] : 0;
        sv.z = (e0 + 2 < n_edges) ? src[e0 + 2] : 0;
        sv.w = 0;
        dv.x = (e0 + 0 < n_edges) ? dst[e0 + 0] : -1;
        dv.y = (e0 + 1 < n_edges) ? dst[e0 + 1] : -1;
        dv.z = (e0 + 2 < n_edges) ? dst[e0 + 2] : -1;
        dv.w = -1;
      }
      es[q * 4 + 0] = sv.x; ed[q * 4 + 0] = dv.x;
      es[q * 4 + 1] = sv.y; ed[q * 4 + 1] = dv.y;
      es[q * 4 + 2] = sv.z; ed[q * 4 + 2] = dv.z;
      es[q * 4 + 3] = sv.w; ed[q * 4 + 3] = dv.w;
    }
#pragma unroll
    for (int k = 0; k < 16; ++k)
      rk[k] = (ed[k] >= 0) ? atomicAdd(&sm.p.lcount[ed[k] >> NBITS], 1) : 0;
    __syncthreads();

    int a = sm.p.lcount[2 * t] + sm.p.lcount[2 * t + 1];
    sm.p.aux[t] = a;
    __syncthreads();
    for (int off = 1; off < 256; off <<= 1) {
      int u = (t >= off) ? sm.p.aux[t - off] : 0;
      __syncthreads();
      sm.p.aux[t] += u;
      __syncthreads();
    }
    int ex = sm.p.aux[t] - a;
    sm.p.lbase[2 * t] = ex;
    sm.p.lbase[2 * t + 1] = ex + sm.p.lcount[2 * t];
    if (t == 255) sm.p.s_total = sm.p.aux[255];
    __syncthreads();

    for (int b = t; b < nb; b += 256)
      sm.p.gbase[b] = (sm.p.lcount[b] > 0)
                          ? ((b << BSHIFT) + atomicAdd(&cursor[b], sm.p.lcount[b]))
                          : 0;
    __syncthreads();

#pragma unroll
    for (int k = 0; k < 16; ++k) {
      if (ed[k] >= 0) {
        int b = ed[k] >> NBITS;
        sm.p.stage[sm.p.lbase[b] + rk[k]] = (unsigned)es[k] | ((unsigned)ed[k] << 16);
      }
    }
    __syncthreads();

    int total = sm.p.s_total;
    for (int r = t; r < total; r += 256) {
      unsigned rec = sm.p.stage[r];
      int b = (int)(rec >> (16 + NBITS));
      recs[sm.p.gbase[b] + (r - sm.p.lbase[b])] = rec;
    }
  }
}

// ---------------- localize: per-bucket counting sort by node -> per-node CSR ----------------
__global__ __launch_bounds__(512) void localize_kernel(
    const unsigned* __restrict__ recs, const int* __restrict__ cursor,
    int* __restrict__ sorted_src, int* __restrict__ row_start,
    int* __restrict__ counts_d, int n_nodes) {
  __shared__ int lc[BNODES];
  __shared__ int ls[BNODES];
  __shared__ int cur[BNODES];
  const int t = threadIdx.x;
  const int b = blockIdx.x;
  const int cbeg = b << BSHIFT;
  const int cnt = cursor[b];

  if (t < BNODES) lc[t] = 0;
  __syncthreads();
  for (int i = t; i < cnt; i += 512) {
    unsigned rec = recs[cbeg + i];
    atomicAdd(&lc[(rec >> 16) & (BNODES - 1)], 1);
  }
  __syncthreads();
  if (t < BNODES) ls[t] = lc[t];
  __syncthreads();
  for (int off = 1; off < BNODES; off <<= 1) {
    int u = (t < BNODES && t >= off) ? ls[t - off] : 0;
    __syncthreads();
    if (t < BNODES) ls[t] += u;
    __syncthreads();
  }
  if (t < BNODES) {
    int ex = ls[t] - lc[t];
    cur[t] = ex;
    int node = (b << NBITS) + t;
    if (node < n_nodes) {
      counts_d[node] = lc[t];
      row_start[node] = cbeg + ex;
    }
  }
  __syncthreads();
  for (int i = t; i < cnt; i += 512) {
    unsigned rec = recs[cbeg + i];
    int nl = (rec >> 16) & (BNODES - 1);
    int p = atomicAdd(&cur[nl], 1);
    sorted_src[cbeg + p] = (int)(rec & 0xffffu);
  }
}

// ---------------- gather-reduce + fused tanh (fp16 Y rows) ----------------
__global__ __launch_bounds__(256) void gather_kernel(
    const unsigned* __restrict__ Yh, const int* __restrict__ sorted_src,
    const int* __restrict__ row_start, const int* __restrict__ counts_d,
    const float* __restrict__ norm, const float* __restrict__ b,
    float* __restrict__ out, int n_nodes) {
  int node = blockIdx.x * 4 + (threadIdx.x >> 6);
  if (node >= n_nodes) return;
  int lane = threadIdx.x & 63;
  int beg = row_start[node];
  int cnt = counts_d[node];
  float accx = 0.f, accy = 0.f;

  for (int base = 0; base < cnt; base += 64) {
    int m = cnt - base;
    if (m > 64) m = 64;
    int myid = (lane < m) ? sorted_src[beg + base + lane] : 0;  // coalesced
    int g = 0;
    for (; g + 16 <= m; g += 16) {
      int sid[16];
      unsigned uu[16];
#pragma unroll
      for (int q = 0; q < 16; ++q) sid[q] = __builtin_amdgcn_readlane(myid, g + q);
#pragma unroll
      for (int q = 0; q < 16; ++q) uu[q] = Yh[(size_t)sid[q] * 64 + lane];
#pragma unroll
      for (int q = 0; q < 16; ++q) {
        float2 v = __half22float2(*reinterpret_cast<__half2*>(&uu[q]));
        accx += v.x;
        accy += v.y;
      }
    }
    for (; g + 8 <= m; g += 8) {
      int sid[8];
      unsigned uu[8];
#pragma unroll
      for (int q = 0; q < 8; ++q) sid[q] = __builtin_amdgcn_readlane(myid, g + q);
#pragma unroll
      for (int q = 0; q < 8; ++q) uu[q] = Yh[(size_t)sid[q] * 64 + lane];
#pragma unroll
      for (int q = 0; q < 8; ++q) {
        float2 v = __half22float2(*reinterpret_cast<__half2*>(&uu[q]));
        accx += v.x;
        accy += v.y;
      }
    }
    for (; g < m; ++g) {
      int s = __builtin_amdgcn_readlane(myid, g);
      unsigned u = Yh[(size_t)s * 64 + lane];
      float2 v = __half22float2(*reinterpret_cast<__half2*>(&u));
      accx += v.x;
      accy += v.y;
    }
  }
  float nm = norm[node];
  float2 bb = ((const float2*)b)[lane];
  float2 h;
  h.x = tanhf(accx * nm + bb.x);
  h.y = tanhf(accy * nm + bb.y);
  ((float2*)out)[(size_t)node * 64 + lane] = h;
}

extern "C" void kernel_launch(void* const* d_in, const int* in_sizes, int n_in,
                              void* d_out, int out_size, void* d_ws, size_t ws_size,
                              hipStream_t stream) {
  const float* feat = (const float*)d_in[0];   // [N,128]
  const float* norm = (const float*)d_in[1];   // [N,1]
  const float* W    = (const float*)d_in[2];   // [128,128]
  const float* b    = (const float*)d_in[3];   // [128]
  const int* src    = (const int*)d_in[4];     // [E]
  const int* dst    = (const int*)d_in[5];     // [E]
  float* out        = (float*)d_out;           // [N,128]

  const int n_nodes = in_sizes[1];
  const int n_edges = in_sizes[4];
  const int nb = (n_nodes + BNODES - 1) / BNODES;   // 391

  // workspace layout
  char* base = (char*)d_ws;
  unsigned* Yh = (unsigned*)base;                   // N*64 uints (fp16-packed rows)
  size_t off = (size_t)n_nodes * 64 * sizeof(unsigned);
  off = (off + 255) & ~(size_t)255;
  int* cursor = (int*)(base + off); off += (size_t)nb * 4;
  off = (off + 255) & ~(size_t)255;
  unsigned* recs = (unsigned*)(base + off); off += ((size_t)nb << BSHIFT) * 4;
  off = (off + 255) & ~(size_t)255;
  int* sorted_src = (int*)(base + off); off += ((size_t)nb << BSHIFT) * 4;
  off = (off + 255) & ~(size_t)255;
  int* row_start = (int*)(base + off); off += (size_t)n_nodes * 4;
  off = (off + 255) & ~(size_t)255;
  int* counts_d = (int*)(base + off); off += (size_t)n_nodes * 4;

  // 0) zero bucket cursors (tiny)
  hipMemsetAsync(cursor, 0, (size_t)nb * sizeof(int), stream);

  // 1) fused: MFMA gemm (blocks 0..gblocks) || edge partition (rest)
  int gblocks = (n_nodes + 63) / 64;
  int chunks = (n_edges + CHUNK - 1) / CHUNK;
  fused_kernel<<<gblocks + chunks, 256, 0, stream>>>(
      feat, norm, W, Yh, n_nodes, src, dst, cursor, recs, n_edges, nb, gblocks);

  // 2) per-bucket counting sort -> per-node CSR
  localize_kernel<<<nb, 512, 0, stream>>>(recs, cursor, sorted_src,
                                          row_start, counts_d, n_nodes);

  // 3) wave-per-node gather-reduce + fused tanh(norm*agg + b)
  int nblocks = (n_nodes + 3) / 4;
  gather_kernel<<<nblocks, 256, 0, stream>>>(Yh, sorted_src, row_start, counts_d,
                                             norm, b, out, n_nodes);
}

// Round 16
// 69.564 us; speedup vs baseline: 10.8736x; 1.0516x over previous
//
#include <hip/hip_runtime.h>
#include <hip/hip_fp16.h>
#include <math.h>

#define NBITS 7            // log2(nodes per bucket)
#define BNODES 128         // nodes per bucket
#define CHUNK 4096         // edges per partition block
#define BSHIFT 12          // fixed bucket stride 4096 records

typedef _Float16 half4v __attribute__((ext_vector_type(4)));
typedef _Float16 half8v __attribute__((ext_vector_type(8)));
typedef float f32x4 __attribute__((ext_vector_type(4)));

__device__ __forceinline__ unsigned hpack(float a, float b) {
  __half2 h = __floats2half2_rn(a, b);
  return *reinterpret_cast<unsigned*>(&h);
}

// ---------------- fused: blocks [0,gblocks) = MFMA GEMM; [gblocks,..) = partition ----------------
union FusedSmem {
  struct {
    _Float16 Wh[128][136];   // [o][k]
    _Float16 Ah[64][136];    // [node][k]
  } g;
  struct {
    int lcount[512];
    int lbase[512];
    int gbase[512];
    int aux[256];
    unsigned stage[CHUNK];
    int s_total;
  } p;
};

__global__ __launch_bounds__(256) void fused_kernel(
    const float* __restrict__ feat, const float* __restrict__ norm,
    const float* __restrict__ W, unsigned* __restrict__ Yh, int n_nodes,
    const int* __restrict__ src, const int* __restrict__ dst,
    int* __restrict__ cursor, unsigned* __restrict__ recs, int n_edges,
    int nb, int gblocks) {
  __shared__ __align__(16) FusedSmem sm;
  const int t = threadIdx.x;

  if ((int)blockIdx.x < gblocks) {
    // ================= GEMM path =================
    const int node0 = blockIdx.x * 64;

#pragma unroll
    for (int k = 0; k < 16; ++k) {
      int e4 = k * 256 + t;
      int oo = e4 >> 5;
      int f4 = (e4 & 31) * 4;
      float4 w = *(const float4*)&W[oo * 128 + f4];
      half4v h;
      h.x = (_Float16)w.x; h.y = (_Float16)w.y;
      h.z = (_Float16)w.z; h.w = (_Float16)w.w;
      *(half4v*)&sm.g.Wh[oo][f4] = h;
    }
#pragma unroll
    for (int k = 0; k < 8; ++k) {
      int e4 = k * 256 + t;
      int nn = e4 >> 5;
      int f4 = (e4 & 31) * 4;
      int node = node0 + nn;
      float4 a = (node < n_nodes)
                     ? *(const float4*)&feat[(size_t)node * 128 + f4]
                     : make_float4(0.f, 0.f, 0.f, 0.f);
      half4v h;
      h.x = (_Float16)a.x; h.y = (_Float16)a.y;
      h.z = (_Float16)a.z; h.w = (_Float16)a.w;
      *(half4v*)&sm.g.Ah[nn][f4] = h;
    }
    __syncthreads();

    const int wv = t >> 6;
    const int l = t & 63;
    const int row16 = l & 15;
    const int kq = l >> 4;

    f32x4 acc[8];
#pragma unroll
    for (int ot = 0; ot < 8; ++ot) acc[ot] = (f32x4){0.f, 0.f, 0.f, 0.f};

#pragma unroll
    for (int ks = 0; ks < 4; ++ks) {
      half8v nfrag = *(const half8v*)&sm.g.Ah[wv * 16 + row16][kq * 8 + ks * 32];
#pragma unroll
      for (int ot = 0; ot < 8; ++ot) {
        half8v wfrag = *(const half8v*)&sm.g.Wh[ot * 16 + row16][kq * 8 + ks * 32];
        acc[ot] = __builtin_amdgcn_mfma_f32_16x16x32_f16(wfrag, nfrag, acc[ot], 0, 0, 0);
      }
    }

    int node = node0 + wv * 16 + row16;
    if (node < n_nodes) {
      float nm = norm[node];
#pragma unroll
      for (int ot = 0; ot < 8; ++ot) {
        uint2 u;
        u.x = hpack(acc[ot][0] * nm, acc[ot][1] * nm);
        u.y = hpack(acc[ot][2] * nm, acc[ot][3] * nm);
        ((uint2*)Yh)[(size_t)node * 32 + ot * 4 + kq] = u;
      }
    }
  } else {
    // ================= partition path =================
    const int cbase = ((int)blockIdx.x - gblocks) * CHUNK;

    sm.p.lcount[t] = 0; sm.p.lcount[t + 256] = 0;
    __syncthreads();

    int es[16], ed[16], rk[16];
#pragma unroll
    for (int q = 0; q < 4; ++q) {
      int i4 = (cbase >> 2) + q * 256 + t;
      int e0 = i4 << 2;
      int4 sv, dv;
      if (e0 + 3 < n_edges) {
        sv = ((const int4*)src)[i4];
        dv = ((const int4*)dst)[i4];
      } else {
        sv.x = (e0 + 0 < n_edges) ? src[e0 + 0] : 0;
        sv.y = (e0 + 1 < n_edges) ? src[e0 + 1] : 0;
        sv.z = (e0 + 2 < n_edges) ? src[e0 + 2] : 0;
        sv.w = 0;
        dv.x = (e0 + 0 < n_edges) ? dst[e0 + 0] : -1;
        dv.y = (e0 + 1 < n_edges) ? dst[e0 + 1] : -1;
        dv.z = (e0 + 2 < n_edges) ? dst[e0 + 2] : -1;
        dv.w = -1;
      }
      es[q * 4 + 0] = sv.x; ed[q * 4 + 0] = dv.x;
      es[q * 4 + 1] = sv.y; ed[q * 4 + 1] = dv.y;
      es[q * 4 + 2] = sv.z; ed[q * 4 + 2] = dv.z;
      es[q * 4 + 3] = sv.w; ed[q * 4 + 3] = dv.w;
    }
#pragma unroll
    for (int k = 0; k < 16; ++k)
      rk[k] = (ed[k] >= 0) ? atomicAdd(&sm.p.lcount[ed[k] >> NBITS], 1) : 0;
    __syncthreads();

    int a = sm.p.lcount[2 * t] + sm.p.lcount[2 * t + 1];
    sm.p.aux[t] = a;
    __syncthreads();
    for (int off = 1; off < 256; off <<= 1) {
      int u = (t >= off) ? sm.p.aux[t - off] : 0;
      __syncthreads();
      sm.p.aux[t] += u;
      __syncthreads();
    }
    int ex = sm.p.aux[t] - a;
    sm.p.lbase[2 * t] = ex;
    sm.p.lbase[2 * t + 1] = ex + sm.p.lcount[2 * t];
    if (t == 255) sm.p.s_total = sm.p.aux[255];
    __syncthreads();

    for (int b = t; b < nb; b += 256)
      sm.p.gbase[b] = (sm.p.lcount[b] > 0)
                          ? ((b << BSHIFT) + atomicAdd(&cursor[b], sm.p.lcount[b]))
                          : 0;
    __syncthreads();

#pragma unroll
    for (int k = 0; k < 16; ++k) {
      if (ed[k] >= 0) {
        int b = ed[k] >> NBITS;
        sm.p.stage[sm.p.lbase[b] + rk[k]] = (unsigned)es[k] | ((unsigned)ed[k] << 16);
      }
    }
    __syncthreads();

    int total = sm.p.s_total;
    for (int r = t; r < total; r += 256) {
      unsigned rec = sm.p.stage[r];
      int b = (int)(rec >> (16 + NBITS));
      recs[sm.p.gbase[b] + (r - sm.p.lbase[b])] = rec;
    }
  }
}

// ---------------- fused localize+gather: 2 blocks per bucket, 512 threads ----------------
// Block (b, half): sorts the half's 64 nodes' src ids into LDS, then gathers.
__global__ __launch_bounds__(512) void lgather_kernel(
    const unsigned* __restrict__ Yh, const unsigned* __restrict__ recs,
    const int* __restrict__ cursor, const float* __restrict__ norm,
    const float* __restrict__ bias, float* __restrict__ out, int n_nodes) {
  __shared__ int lc[64];
  __shared__ int ls[64];
  __shared__ int lbase[64];
  __shared__ int cur[64];
  __shared__ unsigned short sorted_l[1 << BSHIFT];   // 8 KB
  const int t = threadIdx.x;
  const int b = blockIdx.x >> 1;
  const int half = blockIdx.x & 1;
  const int cbeg = b << BSHIFT;
  const int cnt = cursor[b];

  if (t < 64) lc[t] = 0;
  __syncthreads();

  // pass 1: count this half's nodes
  for (int i = t; i < cnt; i += 512) {
    unsigned rec = recs[cbeg + i];
    int nl = (rec >> 16) & (BNODES - 1);
    if ((nl >> 6) == half) atomicAdd(&lc[nl & 63], 1);
  }
  __syncthreads();
  if (t < 64) ls[t] = lc[t];
  __syncthreads();
  for (int off = 1; off < 64; off <<= 1) {
    int u = (t < 64 && t >= off) ? ls[t - off] : 0;
    __syncthreads();
    if (t < 64) ls[t] += u;
    __syncthreads();
  }
  if (t < 64) {
    int ex = ls[t] - lc[t];
    lbase[t] = ex;
    cur[t] = ex;
  }
  __syncthreads();

  // pass 2: scatter this half's src ids into LDS (node-sorted)
  for (int i = t; i < cnt; i += 512) {
    unsigned rec = recs[cbeg + i];
    int nl = (rec >> 16) & (BNODES - 1);
    if ((nl >> 6) == half) {
      int p = atomicAdd(&cur[nl & 63], 1);
      sorted_l[p] = (unsigned short)(rec & 0xffffu);
    }
  }
  __syncthreads();

  // gather: 8 waves x 8 nodes each
  const int wv = t >> 6;
  const int lane = t & 63;
#pragma unroll
  for (int j = 0; j < 8; ++j) {
    int idx = wv * 8 + j;                       // node-local within half
    int node = (b << NBITS) + half * 64 + idx;
    if (node >= n_nodes) continue;
    int beg = lbase[idx];
    int m = lc[idx];
    float accx = 0.f, accy = 0.f;
    for (int base = 0; base < m; base += 64) {
      int mm = m - base;
      if (mm > 64) mm = 64;
      int myid = (lane < mm) ? (int)sorted_l[beg + base + lane] : 0;
      int g = 0;
      for (; g + 8 <= mm; g += 8) {
        int sid[8];
        unsigned uu[8];
#pragma unroll
        for (int q = 0; q < 8; ++q) sid[q] = __builtin_amdgcn_readlane(myid, g + q);
#pragma unroll
        for (int q = 0; q < 8; ++q) uu[q] = Yh[(size_t)sid[q] * 64 + lane];
#pragma unroll
        for (int q = 0; q < 8; ++q) {
          float2 v = __half22float2(*reinterpret_cast<__half2*>(&uu[q]));
          accx += v.x;
          accy += v.y;
        }
      }
      for (; g < mm; ++g) {
        int s = __builtin_amdgcn_readlane(myid, g);
        unsigned u = Yh[(size_t)s * 64 + lane];
        float2 v = __half22float2(*reinterpret_cast<__half2*>(&u));
        accx += v.x;
        accy += v.y;
      }
    }
    float nm = norm[node];
    float2 bb = ((const float2*)bias)[lane];
    float2 h;
    h.x = tanhf(accx * nm + bb.x);
    h.y = tanhf(accy * nm + bb.y);
    ((float2*)out)[(size_t)node * 64 + lane] = h;
  }
}

extern "C" void kernel_launch(void* const* d_in, const int* in_sizes, int n_in,
                              void* d_out, int out_size, void* d_ws, size_t ws_size,
                              hipStream_t stream) {
  const float* feat = (const float*)d_in[0];   // [N,128]
  const float* norm = (const float*)d_in[1];   // [N,1]
  const float* W    = (const float*)d_in[2];   // [128,128]
  const float* b    = (const float*)d_in[3];   // [128]
  const int* src    = (const int*)d_in[4];     // [E]
  const int* dst    = (const int*)d_in[5];     // [E]
  float* out        = (float*)d_out;           // [N,128]

  const int n_nodes = in_sizes[1];
  const int n_edges = in_sizes[4];
  const int nb = (n_nodes + BNODES - 1) / BNODES;   // 391

  // workspace layout
  char* base = (char*)d_ws;
  unsigned* Yh = (unsigned*)base;                   // N*64 uints (fp16-packed rows)
  size_t off = (size_t)n_nodes * 64 * sizeof(unsigned);
  off = (off + 255) & ~(size_t)255;
  int* cursor = (int*)(base + off); off += (size_t)nb * 4;
  off = (off + 255) & ~(size_t)255;
  unsigned* recs = (unsigned*)(base + off); off += ((size_t)nb << BSHIFT) * 4;

  // 0) zero bucket cursors (tiny)
  hipMemsetAsync(cursor, 0, (size_t)nb * sizeof(int), stream);

  // 1) fused: MFMA gemm (blocks 0..gblocks) || edge partition (rest)
  int gblocks = (n_nodes + 63) / 64;
  int chunks = (n_edges + CHUNK - 1) / CHUNK;
  fused_kernel<<<gblocks + chunks, 256, 0, stream>>>(
      feat, norm, W, Yh, n_nodes, src, dst, cursor, recs, n_edges, nb, gblocks);

  // 2) fused localize+gather: 2 blocks/bucket
  lgather_kernel<<<nb * 2, 512, 0, stream>>>(Yh, recs, cursor, norm, b, out, n_nodes);
}

// Round 17
// 68.647 us; speedup vs baseline: 11.0188x; 1.0133x over previous
//
#include <hip/hip_runtime.h>
#include <hip/hip_fp16.h>
#include <math.h>

#define NBITS 7            // log2(nodes per bucket)
#define BNODES 128         // nodes per bucket
#define CHUNK 4096         // edges per partition block
#define BSHIFT 12          // fixed bucket stride 4096 records

typedef _Float16 half4v __attribute__((ext_vector_type(4)));
typedef _Float16 half8v __attribute__((ext_vector_type(8)));
typedef float f32x4 __attribute__((ext_vector_type(4)));

__device__ __forceinline__ unsigned hpack(float a, float b) {
  __half2 h = __floats2half2_rn(a, b);
  return *reinterpret_cast<unsigned*>(&h);
}

// ---------------- fused: blocks [0,gblocks) = MFMA GEMM; [gblocks,..) = partition ----------------
union FusedSmem {
  struct {
    _Float16 Wh[128][136];   // [o][k]
    _Float16 Ah[64][136];    // [node][k]
  } g;
  struct {
    int lcount[512];
    int lbase[512];
    int gbase[512];
    int aux[256];
    unsigned stage[CHUNK];
    int s_total;
  } p;
};

__global__ __launch_bounds__(256) void fused_kernel(
    const float* __restrict__ feat, const float* __restrict__ norm,
    const float* __restrict__ W, unsigned* __restrict__ Yh, int n_nodes,
    const int* __restrict__ src, const int* __restrict__ dst,
    int* __restrict__ cursor, unsigned* __restrict__ recs, int n_edges,
    int nb, int gblocks) {
  __shared__ __align__(16) FusedSmem sm;
  const int t = threadIdx.x;

  if ((int)blockIdx.x < gblocks) {
    // ================= GEMM path =================
    const int node0 = blockIdx.x * 64;

#pragma unroll
    for (int k = 0; k < 16; ++k) {
      int e4 = k * 256 + t;
      int oo = e4 >> 5;
      int f4 = (e4 & 31) * 4;
      float4 w = *(const float4*)&W[oo * 128 + f4];
      half4v h;
      h.x = (_Float16)w.x; h.y = (_Float16)w.y;
      h.z = (_Float16)w.z; h.w = (_Float16)w.w;
      *(half4v*)&sm.g.Wh[oo][f4] = h;
    }
#pragma unroll
    for (int k = 0; k < 8; ++k) {
      int e4 = k * 256 + t;
      int nn = e4 >> 5;
      int f4 = (e4 & 31) * 4;
      int node = node0 + nn;
      float4 a = (node < n_nodes)
                     ? *(const float4*)&feat[(size_t)node * 128 + f4]
                     : make_float4(0.f, 0.f, 0.f, 0.f);
      half4v h;
      h.x = (_Float16)a.x; h.y = (_Float16)a.y;
      h.z = (_Float16)a.z; h.w = (_Float16)a.w;
      *(half4v*)&sm.g.Ah[nn][f4] = h;
    }
    __syncthreads();

    const int wv = t >> 6;
    const int l = t & 63;
    const int row16 = l & 15;
    const int kq = l >> 4;

    f32x4 acc[8];
#pragma unroll
    for (int ot = 0; ot < 8; ++ot) acc[ot] = (f32x4){0.f, 0.f, 0.f, 0.f};

#pragma unroll
    for (int ks = 0; ks < 4; ++ks) {
      half8v nfrag = *(const half8v*)&sm.g.Ah[wv * 16 + row16][kq * 8 + ks * 32];
#pragma unroll
      for (int ot = 0; ot < 8; ++ot) {
        half8v wfrag = *(const half8v*)&sm.g.Wh[ot * 16 + row16][kq * 8 + ks * 32];
        acc[ot] = __builtin_amdgcn_mfma_f32_16x16x32_f16(wfrag, nfrag, acc[ot], 0, 0, 0);
      }
    }

    int node = node0 + wv * 16 + row16;
    if (node < n_nodes) {
      float nm = norm[node];
#pragma unroll
      for (int ot = 0; ot < 8; ++ot) {
        uint2 u;
        u.x = hpack(acc[ot][0] * nm, acc[ot][1] * nm);
        u.y = hpack(acc[ot][2] * nm, acc[ot][3] * nm);
        ((uint2*)Yh)[(size_t)node * 32 + ot * 4 + kq] = u;
      }
    }
  } else {
    // ================= partition path =================
    const int cbase = ((int)blockIdx.x - gblocks) * CHUNK;

    sm.p.lcount[t] = 0; sm.p.lcount[t + 256] = 0;
    __syncthreads();

    int es[16], ed[16], rk[16];
#pragma unroll
    for (int q = 0; q < 4; ++q) {
      int i4 = (cbase >> 2) + q * 256 + t;
      int e0 = i4 << 2;
      int4 sv, dv;
      if (e0 + 3 < n_edges) {
        sv = ((const int4*)src)[i4];
        dv = ((const int4*)dst)[i4];
      } else {
        sv.x = (e0 + 0 < n_edges) ? src[e0 + 0] : 0;
        sv.y = (e0 + 1 < n_edges) ? src[e0 + 1] : 0;
        sv.z = (e0 + 2 < n_edges) ? src[e0 + 2] : 0;
        sv.w = 0;
        dv.x = (e0 + 0 < n_edges) ? dst[e0 + 0] : -1;
        dv.y = (e0 + 1 < n_edges) ? dst[e0 + 1] : -1;
        dv.z = (e0 + 2 < n_edges) ? dst[e0 + 2] : -1;
        dv.w = -1;
      }
      es[q * 4 + 0] = sv.x; ed[q * 4 + 0] = dv.x;
      es[q * 4 + 1] = sv.y; ed[q * 4 + 1] = dv.y;
      es[q * 4 + 2] = sv.z; ed[q * 4 + 2] = dv.z;
      es[q * 4 + 3] = sv.w; ed[q * 4 + 3] = dv.w;
    }
#pragma unroll
    for (int k = 0; k < 16; ++k)
      rk[k] = (ed[k] >= 0) ? atomicAdd(&sm.p.lcount[ed[k] >> NBITS], 1) : 0;
    __syncthreads();

    int a = sm.p.lcount[2 * t] + sm.p.lcount[2 * t + 1];
    sm.p.aux[t] = a;
    __syncthreads();
    for (int off = 1; off < 256; off <<= 1) {
      int u = (t >= off) ? sm.p.aux[t - off] : 0;
      __syncthreads();
      sm.p.aux[t] += u;
      __syncthreads();
    }
    int ex = sm.p.aux[t] - a;
    sm.p.lbase[2 * t] = ex;
    sm.p.lbase[2 * t + 1] = ex + sm.p.lcount[2 * t];
    if (t == 255) sm.p.s_total = sm.p.aux[255];
    __syncthreads();

    for (int b = t; b < nb; b += 256)
      sm.p.gbase[b] = (sm.p.lcount[b] > 0)
                          ? ((b << BSHIFT) + atomicAdd(&cursor[b], sm.p.lcount[b]))
                          : 0;
    __syncthreads();

#pragma unroll
    for (int k = 0; k < 16; ++k) {
      if (ed[k] >= 0) {
        int b = ed[k] >> NBITS;
        sm.p.stage[sm.p.lbase[b] + rk[k]] = (unsigned)es[k] | ((unsigned)ed[k] << 16);
      }
    }
    __syncthreads();

    int total = sm.p.s_total;
    for (int r = t; r < total; r += 256) {
      unsigned rec = sm.p.stage[r];
      int b = (int)(rec >> (16 + NBITS));
      recs[sm.p.gbase[b] + (r - sm.p.lbase[b])] = rec;
    }
  }
}

// ---------------- fused localize+gather: ONE 1024-thread block per bucket ----------------
// Single-pass register-staged localize (recs read once), then 16 waves x 8 nodes gather.
__global__ __launch_bounds__(1024) void lgather_kernel(
    const unsigned* __restrict__ Yh, const unsigned* __restrict__ recs,
    const int* __restrict__ cursor, const float* __restrict__ norm,
    const float* __restrict__ bias, float* __restrict__ out, int n_nodes) {
  __shared__ int lc[BNODES];
  __shared__ int ls[BNODES];
  __shared__ int lbase[BNODES];
  __shared__ int cur[BNODES];
  __shared__ unsigned short sorted_l[1 << BSHIFT];   // 8 KB
  const int t = threadIdx.x;
  const int b = blockIdx.x;
  const int cbeg = b << BSHIFT;
  const int cnt = cursor[b];

  if (t < BNODES) lc[t] = 0;
  __syncthreads();

  // single pass: load up to 4 recs/thread into registers, count
  unsigned r[4];
  int nl[4];
#pragma unroll
  for (int q = 0; q < 4; ++q) {
    int i = q * 1024 + t;
    if (i < cnt) {
      r[q] = recs[cbeg + i];
      nl[q] = (r[q] >> 16) & (BNODES - 1);
      atomicAdd(&lc[nl[q]], 1);
    } else {
      nl[q] = -1;
    }
  }
  __syncthreads();

  // scan 128 bins (first 128 threads)
  if (t < BNODES) ls[t] = lc[t];
  __syncthreads();
  for (int off = 1; off < BNODES; off <<= 1) {
    int u = (t < BNODES && t >= off) ? ls[t - off] : 0;
    __syncthreads();
    if (t < BNODES) ls[t] += u;
    __syncthreads();
  }
  if (t < BNODES) {
    int ex = ls[t] - lc[t];
    lbase[t] = ex;
    cur[t] = ex;
  }
  __syncthreads();

  // scatter from registers into node-sorted LDS
#pragma unroll
  for (int q = 0; q < 4; ++q) {
    if (nl[q] >= 0) {
      int p = atomicAdd(&cur[nl[q]], 1);
      sorted_l[p] = (unsigned short)(r[q] & 0xffffu);
    }
  }
  __syncthreads();

  // gather: 16 waves x 8 nodes each
  const int wv = t >> 6;
  const int lane = t & 63;
#pragma unroll
  for (int j = 0; j < 8; ++j) {
    int idx = wv * 8 + j;                       // node-local 0..127
    int node = (b << NBITS) + idx;
    if (node >= n_nodes) continue;
    int beg = lbase[idx];
    int m = lc[idx];
    float accx = 0.f, accy = 0.f;
    for (int base = 0; base < m; base += 64) {
      int mm = m - base;
      if (mm > 64) mm = 64;
      int myid = (lane < mm) ? (int)sorted_l[beg + base + lane] : 0;
      int g = 0;
      for (; g + 8 <= mm; g += 8) {
        int sid[8];
        unsigned uu[8];
#pragma unroll
        for (int q = 0; q < 8; ++q) sid[q] = __builtin_amdgcn_readlane(myid, g + q);
#pragma unroll
        for (int q = 0; q < 8; ++q) uu[q] = Yh[(size_t)sid[q] * 64 + lane];
#pragma unroll
        for (int q = 0; q < 8; ++q) {
          float2 v = __half22float2(*reinterpret_cast<__half2*>(&uu[q]));
          accx += v.x;
          accy += v.y;
        }
      }
      for (; g < mm; ++g) {
        int s = __builtin_amdgcn_readlane(myid, g);
        unsigned u = Yh[(size_t)s * 64 + lane];
        float2 v = __half22float2(*reinterpret_cast<__half2*>(&u));
        accx += v.x;
        accy += v.y;
      }
    }
    float nm = norm[node];
    float2 bb = ((const float2*)bias)[lane];
    float2 h;
    h.x = tanhf(accx * nm + bb.x);
    h.y = tanhf(accy * nm + bb.y);
    ((float2*)out)[(size_t)node * 64 + lane] = h;
  }
}

extern "C" void kernel_launch(void* const* d_in, const int* in_sizes, int n_in,
                              void* d_out, int out_size, void* d_ws, size_t ws_size,
                              hipStream_t stream) {
  const float* feat = (const float*)d_in[0];   // [N,128]
  const float* norm = (const float*)d_in[1];   // [N,1]
  const float* W    = (const float*)d_in[2];   // [128,128]
  const float* b    = (const float*)d_in[3];   // [128]
  const int* src    = (const int*)d_in[4];     // [E]
  const int* dst    = (const int*)d_in[5];     // [E]
  float* out        = (float*)d_out;           // [N,128]

  const int n_nodes = in_sizes[1];
  const int n_edges = in_sizes[4];
  const int nb = (n_nodes + BNODES - 1) / BNODES;   // 391

  // workspace layout
  char* base = (char*)d_ws;
  unsigned* Yh = (unsigned*)base;                   // N*64 uints (fp16-packed rows)
  size_t off = (size_t)n_nodes * 64 * sizeof(unsigned);
  off = (off + 255) & ~(size_t)255;
  int* cursor = (int*)(base + off); off += (size_t)nb * 4;
  off = (off + 255) & ~(size_t)255;
  unsigned* recs = (unsigned*)(base + off); off += ((size_t)nb << BSHIFT) * 4;

  // 0) zero bucket cursors (tiny)
  hipMemsetAsync(cursor, 0, (size_t)nb * sizeof(int), stream);

  // 1) fused: MFMA gemm (blocks 0..gblocks) || edge partition (rest)
  int gblocks = (n_nodes + 63) / 64;
  int chunks = (n_edges + CHUNK - 1) / CHUNK;
  fused_kernel<<<gblocks + chunks, 256, 0, stream>>>(
      feat, norm, W, Yh, n_nodes, src, dst, cursor, recs, n_edges, nb, gblocks);

  // 2) fused localize+gather: one 1024-thread block per bucket
  lgather_kernel<<<nb, 1024, 0, stream>>>(Yh, recs, cursor, norm, b, out, n_nodes);
}